// Round 13
// baseline (1924.769 us; speedup 1.0000x reference)
//
#include <hip/hip_runtime.h>

#define N_NODES 50000
#define N_EDGES 1600000

// weight offsets (floats) inside the weights region of d_ws
#define O_ENCW0 0
#define O_ENCB0 108
#define O_ENCW1 126
#define O_ENCB1 450
#define O_ENCW2 468
#define O_ENCB2 756
#define O_EDGEW0 772
#define O_EDGEB0 13572
#define O_EDGEW1 13652
#define O_EDGEB1 14932
#define O_NODEW0 14948
#define O_NODEB0 19428
#define O_NODEW1 19484
#define O_NODEB1 21276
#define W_TOTAL 21308

typedef __attribute__((ext_vector_type(8))) short bf16x8;
typedef __attribute__((ext_vector_type(4))) short bf16x4;
typedef __attribute__((ext_vector_type(4))) float f32x4;

__device__ __forceinline__ float bf2f(unsigned int u) {
    return __uint_as_float(u << 16);
}
__device__ __forceinline__ unsigned short f2bf(float f) {
    unsigned int u = __float_as_uint(f);
    u += 0x7fffu + ((u >> 16) & 1u);   // RNE (finite values only here)
    return (unsigned short)(u >> 16);
}
__device__ __forceinline__ float lrelu(float x) { return x > 0.f ? x : 0.01f * x; }

__device__ __forceinline__ bf16x8 pack8(float4 a, float4 b) {
    bf16x8 r;
    r[0] = (short)f2bf(a.x); r[1] = (short)f2bf(a.y);
    r[2] = (short)f2bf(a.z); r[3] = (short)f2bf(a.w);
    r[4] = (short)f2bf(b.x); r[5] = (short)f2bf(b.y);
    r[6] = (short)f2bf(b.z); r[7] = (short)f2bf(b.w);
    return r;
}

struct WPack {
    const float* p[14];
    int off[15];
};

// ---- detect flag: edge_index is int64 (high words of first 64 entries all zero) ----
__global__ void detect_flags(const int* __restrict__ eidx, int* __restrict__ flags) {
    int t = threadIdx.x;  // 64 threads
    int v = eidx[2 * t + 1];
    unsigned long long bi = __ballot(v != 0);
    if (t == 0) flags[0] = (bi == 0ull) ? 1 : 0;
}

__device__ __forceinline__ void load_rc(const int* eidx, int flag64, int e, int& r, int& c) {
    if (flag64) {
        const long long* e64 = (const long long*)eidx;
        r = (int)e64[e];
        c = (int)e64[N_EDGES + e];
    } else {
        r = eidx[e];
        c = eidx[N_EDGES + e];
    }
}
__device__ __forceinline__ int load_r(const int* eidx, int flag64, int e) {
    return flag64 ? (int)((const long long*)eidx)[e] : eidx[e];
}

// ---- copy all f32 weight/bias arrays into contiguous ws region ----
__global__ void copy_w(WPack P, float* __restrict__ dst) {
    int a = blockIdx.x;
    const float* s = P.p[a];
    int n = P.off[a + 1] - P.off[a];
    float* d = dst + P.off[a];
    for (int i = threadIdx.x; i < n; i += 256) d[i] = s[i];
}

// ---- build transposed bf16 weights for MFMA B-fragments ----
// wT[0..12799]      = W0T [80 cols][160 k]  (W0 f32 [160][80] row-major)
// wT[12800..14335]  = W1T [16 cols][96 k]   (W1 f32 [80][16]; k 80..95 zero)
__global__ void build_wT(const float* __restrict__ w0,
                         const float* __restrict__ w1,
                         unsigned short* __restrict__ wT) {
    int t = blockIdx.x * 256 + threadIdx.x;  // 56 * 256 = 14336
    if (t < 12800) {
        int col = t / 160, k = t % 160;
        wT[t] = f2bf(w0[k * 80 + col]);
    } else if (t < 14336) {
        int u = t - 12800;
        int col = u / 96, k = u % 96;
        wT[t] = (k < 80) ? f2bf(w1[k * 16 + col]) : (unsigned short)0;
    }
}

// ---- n0 = lrelu(x) (f32 in) stored bf16; ncb = [n0, n0]; zero cnti ----
__global__ void __launch_bounds__(256) init_nodes(const float* __restrict__ x,
                                                  unsigned short* __restrict__ ncb,
                                                  int* __restrict__ cnti) {
    int i = blockIdx.x * 256 + threadIdx.x;
    if (i >= N_NODES) return;
    const float4* xin = (const float4*)(x + (size_t)i * 32);  // 8 float4
    uint4* np = (uint4*)(ncb + (size_t)i * 64);
#pragma unroll
    for (int q = 0; q < 4; q++) {
        float4 a = xin[2 * q];
        float4 b = xin[2 * q + 1];
        unsigned int w0 = (unsigned int)f2bf(lrelu(a.x)) | ((unsigned int)f2bf(lrelu(a.y)) << 16);
        unsigned int w1 = (unsigned int)f2bf(lrelu(a.z)) | ((unsigned int)f2bf(lrelu(a.w)) << 16);
        unsigned int w2 = (unsigned int)f2bf(lrelu(b.x)) | ((unsigned int)f2bf(lrelu(b.y)) << 16);
        unsigned int w3 = (unsigned int)f2bf(lrelu(b.z)) | ((unsigned int)f2bf(lrelu(b.w)) << 16);
        uint4 o = make_uint4(w0, w1, w2, w3);
        np[q] = o;       // n0 half (bf16)
        np[4 + q] = o;   // n half (n == n0 initially)
    }
    cnti[i] = 0;
}

// ---- CSR build: count, scan, bucket ----
__global__ void count_edges(const int* __restrict__ eidx, const int* __restrict__ flags,
                            int* __restrict__ cnti) {
    int e = blockIdx.x * 256 + threadIdx.x;
    atomicAdd(&cnti[load_r(eidx, flags[0], e)], 1);
}

// one block, 256 threads; each thread scans a 196-node chunk (256*196 >= 50000)
__global__ void __launch_bounds__(256) scan_offsets(const int* __restrict__ cnti,
                                                    int* __restrict__ off,
                                                    int* __restrict__ cursor) {
    __shared__ int ls[256];
    const int t = threadIdx.x;
    const int lo = t * 196;
    const int hi = min(lo + 196, N_NODES);
    int sum = 0;
    for (int i = lo; i < hi; i++) sum += cnti[i];
    ls[t] = sum;
    __syncthreads();
    for (int d = 1; d < 256; d <<= 1) {
        int v = (t >= d) ? ls[t - d] : 0;
        __syncthreads();
        ls[t] += v;
        __syncthreads();
    }
    int run = (t == 0) ? 0 : ls[t - 1];
    for (int i = lo; i < hi; i++) {
        off[i] = run;
        cursor[i] = run;
        run += cnti[i];
    }
    if (t == 255) off[N_NODES] = run;   // == N_EDGES
}

__global__ void build_perm(const int* __restrict__ eidx, const int* __restrict__ flags,
                           int* __restrict__ cursor, int* __restrict__ perm) {
    int e = blockIdx.x * 256 + threadIdx.x;
    int pos = atomicAdd(&cursor[load_r(eidx, flags[0], e)], 1);
    perm[pos] = e;
}

// ---- encoder MLP 6->18->18->16 (lrelu each); e0 (f32) -> slot 4 of out ----
__global__ void __launch_bounds__(256) encoder(const float* __restrict__ ea,
                                               const float* __restrict__ wsW,
                                               float* __restrict__ outbase) {
    int e = blockIdx.x * 256 + threadIdx.x;  // E % 256 == 0
    const float* ap = ea + (size_t)e * 6;
    float a[6];
#pragma unroll
    for (int k = 0; k < 6; k++) a[k] = ap[k];

    float h1[18];
#pragma unroll
    for (int j = 0; j < 18; j++) h1[j] = wsW[O_ENCB0 + j];
#pragma unroll
    for (int k = 0; k < 6; k++) {
        float v = a[k];
#pragma unroll
        for (int j = 0; j < 18; j++) h1[j] = fmaf(v, wsW[O_ENCW0 + k * 18 + j], h1[j]);
    }
#pragma unroll
    for (int j = 0; j < 18; j++) h1[j] = lrelu(h1[j]);

    float h2[18];
#pragma unroll
    for (int j = 0; j < 18; j++) h2[j] = wsW[O_ENCB1 + j];
#pragma unroll
    for (int k = 0; k < 18; k++) {
        float v = h1[k];
#pragma unroll
        for (int j = 0; j < 18; j++) h2[j] = fmaf(v, wsW[O_ENCW1 + k * 18 + j], h2[j]);
    }
#pragma unroll
    for (int j = 0; j < 18; j++) h2[j] = lrelu(h2[j]);

    float o[16];
#pragma unroll
    for (int j = 0; j < 16; j++) o[j] = wsW[O_ENCB2 + j];
#pragma unroll
    for (int k = 0; k < 18; k++) {
        float v = h2[k];
#pragma unroll
        for (int j = 0; j < 16; j++) o[j] = fmaf(v, wsW[O_ENCW2 + k * 16 + j], o[j]);
    }
    float4* ow = (float4*)(outbase + (size_t)4 * N_EDGES * 16 + (size_t)e * 16);
#pragma unroll
    for (int q = 0; q < 4; q++)
        ow[q] = make_float4(lrelu(o[4 * q]), lrelu(o[4 * q + 1]),
                            lrelu(o[4 * q + 2]), lrelu(o[4 * q + 3]));
}

// ---- edge update: BOTH layers MFMA; QUAD 16-edge groups per wave, 2 halves ----
// 256 thr = 4 waves; wave owns 64 edges (4 groups); block 256 edges; grid 6250.
// All 20 A-gather loads issued up front (max memory-level parallelism).
// Layer1/layer2 run in two halves reusing the same per-wave act1 rows (LDS 26.6 KB).
// MFMA 16x16x32 frags (m97/m89-verified): A row=lane&15, k=st*32+(lane>>4)*8+j;
// B col=lane&15, same k; D col=lane&15, row=4*(lane>>4)+reg.
// Same-wave DS ops are in-order; lgkmcnt+sched_barrier fences guard the compiler
// (rule #18). In-place slot step safe: half-h stores touch [ebase+h*32,+32),
// pending half-1 loads touch [ebase+32,+64) only at h=0 -> disjoint per wave.
__global__ void __launch_bounds__(256) edge_mfma(const unsigned short* __restrict__ ncb,
                                                 const float* __restrict__ outb_c,
                                                 int slot_e0, int slot_prev, int slot_cur,
                                                 const int* __restrict__ eidx,
                                                 const int* __restrict__ flags,
                                                 const float* __restrict__ wsW,
                                                 const unsigned short* __restrict__ wT,
                                                 float* __restrict__ outb) {
    __shared__ unsigned short act1[4][32 * 104];  // 26.6 KB total
    const int lane = threadIdx.x & 63;
    const int wave = threadIdx.x >> 6;
    const int r16 = lane & 15;
    const int g = lane >> 4;
    const int flag64 = flags[0];
    unsigned short* aw = act1[wave];

    const int ebase = blockIdx.x * 256 + wave * 64;
    const float* e0s = outb_c + (size_t)slot_e0 * N_EDGES * 16;
    const float* eps = outb_c + (size_t)slot_prev * N_EDGES * 16;

    // zero K-pad (k 80..95) for both j-halves' rows (persists across halves)
#pragma unroll
    for (int j = 0; j < 2; j++) {
        bf16x4 z4 = {0, 0, 0, 0};
        *(bf16x4*)&aw[(j * 16 + r16) * 104 + 80 + g * 4] = z4;
    }

    // ---- gather A-fragments for all 4 groups up front (20 loads in flight) ----
    bf16x8 a[4][5];
#pragma unroll
    for (int u = 0; u < 4; u++) {
        const int el = ebase + u * 16 + r16;
        int r_el, c_el;
        load_rc(eidx, flag64, el, r_el, c_el);
        a[u][0] = *(const bf16x8*)(ncb + (size_t)r_el * 64 + g * 8);
        a[u][1] = *(const bf16x8*)(ncb + (size_t)r_el * 64 + 32 + g * 8);
        a[u][2] = *(const bf16x8*)(ncb + (size_t)c_el * 64 + g * 8);
        a[u][3] = *(const bf16x8*)(ncb + (size_t)c_el * 64 + 32 + g * 8);
        const float* src = (g < 2) ? e0s : eps;
        const float4* p = (const float4*)(src + (size_t)el * 16 + (g & 1) * 8);
        a[u][4] = pack8(p[0], p[1]);
    }

    // layer-2 B fragments: shared by all 4 groups, load once
    bf16x8 bb2[3];
#pragma unroll
    for (int st = 0; st < 3; st++)
        bb2[st] = *(const bf16x8*)(wT + 12800 + r16 * 96 + st * 32 + g * 8);
    const float bv2 = wsW[O_EDGEB1 + r16];
    float* oc = outb + (size_t)slot_cur * N_EDGES * 16;

#pragma unroll
    for (int h = 0; h < 2; h++) {
        // ---- layer 1 for groups 2h, 2h+1: B loaded once, 2 MFMA per B ----
#pragma unroll
        for (int t = 0; t < 5; t++) {
            float bv = wsW[O_EDGEB0 + t * 16 + r16];
            f32x4 acc0 = {bv, bv, bv, bv};
            f32x4 acc1 = {bv, bv, bv, bv};
#pragma unroll
            for (int st = 0; st < 5; st++) {
                bf16x8 b = *(const bf16x8*)(wT + (t * 16 + r16) * 160 + st * 32 + g * 8);
                acc0 = __builtin_amdgcn_mfma_f32_16x16x32_bf16(a[2 * h][st], b, acc0, 0, 0, 0);
                acc1 = __builtin_amdgcn_mfma_f32_16x16x32_bf16(a[2 * h + 1][st], b, acc1, 0, 0, 0);
            }
#pragma unroll
            for (int i = 0; i < 4; i++) {
                aw[(g * 4 + i) * 104 + t * 16 + r16]      = f2bf(lrelu(acc0[i]));
                aw[(16 + g * 4 + i) * 104 + t * 16 + r16] = f2bf(lrelu(acc1[i]));
            }
        }
        asm volatile("s_waitcnt lgkmcnt(0)" ::: "memory");
        __builtin_amdgcn_sched_barrier(0);

        // ---- layer 2 for this half's two groups (K=96, 3 MFMA each) ----
#pragma unroll
        for (int j = 0; j < 2; j++) {
            f32x4 acc2 = {bv2, bv2, bv2, bv2};
#pragma unroll
            for (int st = 0; st < 3; st++) {
                bf16x8 a2 = *(const bf16x8*)&aw[(j * 16 + r16) * 104 + st * 32 + g * 8];
                acc2 = __builtin_amdgcn_mfma_f32_16x16x32_bf16(a2, bb2[st], acc2, 0, 0, 0);
            }
#pragma unroll
            for (int i = 0; i < 4; i++) {
                int eg = ebase + (2 * h + j) * 16 + g * 4 + i;
                oc[(size_t)eg * 16 + r16] = lrelu(acc2[i]);
            }
        }
        if (h == 0) {
            // drain this half's act1 reads before next half overwrites the rows
            asm volatile("s_waitcnt lgkmcnt(0)" ::: "memory");
            __builtin_amdgcn_sched_barrier(0);
        }
    }
}

// ---- gather-mean: one wave per node; msg[i] = mean of e[perm[p0..p1]] ----
__global__ void __launch_bounds__(256) gather_mean(const int* __restrict__ off,
                                                   const int* __restrict__ perm,
                                                   const float* __restrict__ ecur,
                                                   float* __restrict__ msg) {
    const int wave = threadIdx.x >> 6;
    const int lane = threadIdx.x & 63;
    const int i = blockIdx.x * 4 + wave;   // 12500 * 4 = 50000 exactly
    const int c = lane & 15;
    const int sub = lane >> 4;
    const int p0 = off[i], p1 = off[i + 1];
    float sum = 0.f;
    for (int p = p0 + sub; p < p1; p += 4)
        sum += ecur[(size_t)perm[p] * 16 + c];
    sum += __shfl_xor(sum, 16, 64);
    sum += __shfl_xor(sum, 32, 64);
    if (lane < 16) {
        float inv = 1.0f / fmaxf((float)(p1 - p0), 1.0f);
        msg[(size_t)i * 16 + c] = sum * inv;
    }
}

// ---- node MLP: nh=[nc(bf16->f32), msg] (80) -> 56 (relu) -> 32 (relu) ----
__global__ void __launch_bounds__(64) node_mlp(const float* __restrict__ msg,
                                               unsigned short* __restrict__ ncb,
                                               const float* __restrict__ wsW) {
    __shared__ float sl[64 * 81];
    const int l = threadIdx.x;
    const int i = blockIdx.x * 64 + l;
    if (i >= N_NODES) return;
    const float* W0 = wsW + O_NODEW0;
    const float* b0 = wsW + O_NODEB0;
    const float* W1 = wsW + O_NODEW1;
    const float* b1 = wsW + O_NODEB1;

    const uint4* ncp = (const uint4*)(ncb + (size_t)i * 64);
#pragma unroll
    for (int q = 0; q < 8; q++) {
        uint4 u = ncp[q];
        int base = l * 81 + 8 * q;
        sl[base + 0] = bf2f(u.x & 0xffffu); sl[base + 1] = bf2f(u.x >> 16);
        sl[base + 2] = bf2f(u.y & 0xffffu); sl[base + 3] = bf2f(u.y >> 16);
        sl[base + 4] = bf2f(u.z & 0xffffu); sl[base + 5] = bf2f(u.z >> 16);
        sl[base + 6] = bf2f(u.w & 0xffffu); sl[base + 7] = bf2f(u.w >> 16);
    }
    const float4* mp = (const float4*)(msg + (size_t)i * 16);
#pragma unroll
    for (int q = 0; q < 4; q++) {
        float4 v = mp[q];
        int base = l * 81 + 64 + 4 * q;
        sl[base] = v.x; sl[base + 1] = v.y; sl[base + 2] = v.z; sl[base + 3] = v.w;
    }

    float h[56];
#pragma unroll
    for (int q = 0; q < 14; q++) {
        float4 b = ((const float4*)b0)[q];
        h[4 * q] = b.x; h[4 * q + 1] = b.y; h[4 * q + 2] = b.z; h[4 * q + 3] = b.w;
    }
    for (int k = 0; k < 80; k++) {
        float v = sl[l * 81 + k];
        const float4* w = (const float4*)(W0 + k * 56);
#pragma unroll
        for (int q = 0; q < 14; q++) {
            float4 wv = w[q];
            h[4 * q]     = fmaf(v, wv.x, h[4 * q]);
            h[4 * q + 1] = fmaf(v, wv.y, h[4 * q + 1]);
            h[4 * q + 2] = fmaf(v, wv.z, h[4 * q + 2]);
            h[4 * q + 3] = fmaf(v, wv.w, h[4 * q + 3]);
        }
    }
#pragma unroll
    for (int j = 0; j < 56; j++) sl[l * 81 + j] = fmaxf(h[j], 0.f);

    float o[32];
#pragma unroll
    for (int q = 0; q < 8; q++) {
        float4 b = ((const float4*)b1)[q];
        o[4 * q] = b.x; o[4 * q + 1] = b.y; o[4 * q + 2] = b.z; o[4 * q + 3] = b.w;
    }
    for (int j = 0; j < 56; j++) {
        float v = sl[l * 81 + j];
        const float4* w = (const float4*)(W1 + j * 32);
#pragma unroll
        for (int q = 0; q < 8; q++) {
            float4 wv = w[q];
            o[4 * q]     = fmaf(v, wv.x, o[4 * q]);
            o[4 * q + 1] = fmaf(v, wv.y, o[4 * q + 1]);
            o[4 * q + 2] = fmaf(v, wv.z, o[4 * q + 2]);
            o[4 * q + 3] = fmaf(v, wv.w, o[4 * q + 3]);
        }
    }
    // write n half back as bf16
    uint4* nout = (uint4*)(ncb + (size_t)i * 64 + 32);
#pragma unroll
    for (int q = 0; q < 4; q++) {
        unsigned int w0 = (unsigned int)f2bf(fmaxf(o[8 * q + 0], 0.f)) |
                          ((unsigned int)f2bf(fmaxf(o[8 * q + 1], 0.f)) << 16);
        unsigned int w1 = (unsigned int)f2bf(fmaxf(o[8 * q + 2], 0.f)) |
                          ((unsigned int)f2bf(fmaxf(o[8 * q + 3], 0.f)) << 16);
        unsigned int w2 = (unsigned int)f2bf(fmaxf(o[8 * q + 4], 0.f)) |
                          ((unsigned int)f2bf(fmaxf(o[8 * q + 5], 0.f)) << 16);
        unsigned int w3 = (unsigned int)f2bf(fmaxf(o[8 * q + 6], 0.f)) |
                          ((unsigned int)f2bf(fmaxf(o[8 * q + 7], 0.f)) << 16);
        nout[q] = make_uint4(w0, w1, w2, w3);
    }
}

extern "C" void kernel_launch(void* const* d_in, const int* in_sizes, int n_in,
                              void* d_out, int out_size, void* d_ws, size_t ws_size,
                              hipStream_t stream) {
    (void)in_sizes; (void)n_in; (void)out_size;
    const float* x  = (const float*)d_in[0];
    const int* eidx = (const int*)d_in[1];
    const float* ea = (const float*)d_in[2];
    float* out = (float*)d_out;   // f32 output: 5 slots x E x 16

    // d_ws layout (byte offsets):
    //   wsW @0 (85232) | flags @85232 (16) | cnti @85248 (200000) | off @285248 (200016)
    //   cursor @485264 (200000) | perm @685264 (6400000) | ncb @7085264 (6400000, u16)
    //   wT @13485264 (28672, u16) | msg @13513936 (3200000, f32)
    char* wsb = (char*)d_ws;
    float* wsW  = (float*)(wsb + 0);
    int* flags  = (int*)(wsb + 85232);
    int* cnti   = (int*)(wsb + 85248);
    int* off    = (int*)(wsb + 285248);
    int* cursor = (int*)(wsb + 485264);
    int* perm   = (int*)(wsb + 685264);
    unsigned short* ncb = (unsigned short*)(wsb + 7085264);
    unsigned short* wT  = (unsigned short*)(wsb + 13485264);
    float* msg  = (float*)(wsb + 13513936);
    const size_t WS_NEEDED = 16713936ull;
    if (ws_size < WS_NEEDED) return;  // refuse to corrupt memory

    WPack P;
    static const int offs[15] = {0, 108, 126, 450, 468, 756, 772, 13572, 13652,
                                 14932, 14948, 19428, 19484, 21276, 21308};
    for (int a = 0; a < 14; a++) P.p[a] = (const float*)d_in[3 + a];
    for (int a = 0; a < 15; a++) P.off[a] = offs[a];

    detect_flags<<<1, 64, 0, stream>>>(eidx, flags);
    copy_w<<<14, 256, 0, stream>>>(P, wsW);
    build_wT<<<56, 256, 0, stream>>>((const float*)d_in[9], (const float*)d_in[11], wT);
    init_nodes<<<196, 256, 0, stream>>>(x, ncb, cnti);
    count_edges<<<N_EDGES / 256, 256, 0, stream>>>(eidx, flags, cnti);
    scan_offsets<<<1, 256, 0, stream>>>(cnti, off, cursor);
    build_perm<<<N_EDGES / 256, 256, 0, stream>>>(eidx, flags, cursor, perm);
    encoder<<<N_EDGES / 256, 256, 0, stream>>>(ea, wsW, out);

    // e-history in f32 d_out slots; final out[j] = e_{j+2}
    // t=1: e0(s4)->s0; t=2: s0->s0; t=3: s0->s1; t=4: s1->s2; t=5: s2->s3; t=6: s3->s4
    const int prevs[6] = {4, 0, 0, 1, 2, 3};
    const int curs[6]  = {0, 0, 1, 2, 3, 4};

    for (int t = 1; t <= 6; t++) {
        edge_mfma<<<N_EDGES / 256, 256, 0, stream>>>(ncb, out, 4, prevs[t - 1],
                                                     curs[t - 1], eidx, flags, wsW,
                                                     wT, out);
        if (t < 6) {
            gather_mean<<<12500, 256, 0, stream>>>(off, perm,
                                                   out + (size_t)curs[t - 1] * N_EDGES * 16,
                                                   msg);
            node_mlp<<<782, 64, 0, stream>>>(msg, ncb, wsW);
        }
    }
}

// Round 14
// 1763.873 us; speedup vs baseline: 1.0912x; 1.0912x over previous
//
#include <hip/hip_runtime.h>

#define N_NODES 50000
#define N_EDGES 1600000

// weight offsets (floats) inside the weights region of d_ws
#define O_ENCW0 0
#define O_ENCB0 108
#define O_ENCW1 126
#define O_ENCB1 450
#define O_ENCW2 468
#define O_ENCB2 756
#define O_EDGEW0 772
#define O_EDGEB0 13572
#define O_EDGEW1 13652
#define O_EDGEB1 14932
#define O_NODEW0 14948
#define O_NODEB0 19428
#define O_NODEW1 19484
#define O_NODEB1 21276
#define W_TOTAL 21308

typedef __attribute__((ext_vector_type(8))) short bf16x8;
typedef __attribute__((ext_vector_type(4))) short bf16x4;
typedef __attribute__((ext_vector_type(4))) float f32x4;

__device__ __forceinline__ float bf2f(unsigned int u) {
    return __uint_as_float(u << 16);
}
__device__ __forceinline__ unsigned short f2bf(float f) {
    unsigned int u = __float_as_uint(f);
    u += 0x7fffu + ((u >> 16) & 1u);   // RNE (finite values only here)
    return (unsigned short)(u >> 16);
}
__device__ __forceinline__ float lrelu(float x) { return x > 0.f ? x : 0.01f * x; }

__device__ __forceinline__ bf16x8 pack8(float4 a, float4 b) {
    bf16x8 r;
    r[0] = (short)f2bf(a.x); r[1] = (short)f2bf(a.y);
    r[2] = (short)f2bf(a.z); r[3] = (short)f2bf(a.w);
    r[4] = (short)f2bf(b.x); r[5] = (short)f2bf(b.y);
    r[6] = (short)f2bf(b.z); r[7] = (short)f2bf(b.w);
    return r;
}

struct WPack {
    const float* p[14];
    int off[15];
};

// ---- detect flag: edge_index is int64 (high words of first 64 entries all zero) ----
__global__ void detect_flags(const int* __restrict__ eidx, int* __restrict__ flags) {
    int t = threadIdx.x;  // 64 threads
    int v = eidx[2 * t + 1];
    unsigned long long bi = __ballot(v != 0);
    if (t == 0) flags[0] = (bi == 0ull) ? 1 : 0;
}

__device__ __forceinline__ void load_rc(const int* eidx, int flag64, int e, int& r, int& c) {
    if (flag64) {
        const long long* e64 = (const long long*)eidx;
        r = (int)e64[e];
        c = (int)e64[N_EDGES + e];
    } else {
        r = eidx[e];
        c = eidx[N_EDGES + e];
    }
}
__device__ __forceinline__ int load_r(const int* eidx, int flag64, int e) {
    return flag64 ? (int)((const long long*)eidx)[e] : eidx[e];
}

// ---- copy all f32 weight/bias arrays into contiguous ws region ----
__global__ void copy_w(WPack P, float* __restrict__ dst) {
    int a = blockIdx.x;
    const float* s = P.p[a];
    int n = P.off[a + 1] - P.off[a];
    float* d = dst + P.off[a];
    for (int i = threadIdx.x; i < n; i += 256) d[i] = s[i];
}

// ---- build transposed bf16 weights for MFMA B-fragments ----
// wT[0..12799]      = W0T [80 cols][160 k]  (W0 f32 [160][80] row-major)
// wT[12800..14335]  = W1T [16 cols][96 k]   (W1 f32 [80][16]; k 80..95 zero)
__global__ void build_wT(const float* __restrict__ w0,
                         const float* __restrict__ w1,
                         unsigned short* __restrict__ wT) {
    int t = blockIdx.x * 256 + threadIdx.x;  // 56 * 256 = 14336
    if (t < 12800) {
        int col = t / 160, k = t % 160;
        wT[t] = f2bf(w0[k * 80 + col]);
    } else if (t < 14336) {
        int u = t - 12800;
        int col = u / 96, k = u % 96;
        wT[t] = (k < 80) ? f2bf(w1[k * 16 + col]) : (unsigned short)0;
    }
}

// ---- n0 = lrelu(x) (f32 in) stored bf16; ncb = [n0, n0]; zero cnti ----
__global__ void __launch_bounds__(256) init_nodes(const float* __restrict__ x,
                                                  unsigned short* __restrict__ ncb,
                                                  int* __restrict__ cnti) {
    int i = blockIdx.x * 256 + threadIdx.x;
    if (i >= N_NODES) return;
    const float4* xin = (const float4*)(x + (size_t)i * 32);  // 8 float4
    uint4* np = (uint4*)(ncb + (size_t)i * 64);
#pragma unroll
    for (int q = 0; q < 4; q++) {
        float4 a = xin[2 * q];
        float4 b = xin[2 * q + 1];
        unsigned int w0 = (unsigned int)f2bf(lrelu(a.x)) | ((unsigned int)f2bf(lrelu(a.y)) << 16);
        unsigned int w1 = (unsigned int)f2bf(lrelu(a.z)) | ((unsigned int)f2bf(lrelu(a.w)) << 16);
        unsigned int w2 = (unsigned int)f2bf(lrelu(b.x)) | ((unsigned int)f2bf(lrelu(b.y)) << 16);
        unsigned int w3 = (unsigned int)f2bf(lrelu(b.z)) | ((unsigned int)f2bf(lrelu(b.w)) << 16);
        uint4 o = make_uint4(w0, w1, w2, w3);
        np[q] = o;       // n0 half (bf16)
        np[4 + q] = o;   // n half (n == n0 initially)
    }
    cnti[i] = 0;
}

// ---- CSR build: count, scan, bucket ----
__global__ void count_edges(const int* __restrict__ eidx, const int* __restrict__ flags,
                            int* __restrict__ cnti) {
    int e = blockIdx.x * 256 + threadIdx.x;
    atomicAdd(&cnti[load_r(eidx, flags[0], e)], 1);
}

// one block, 256 threads; each thread scans a 196-node chunk (256*196 >= 50000)
__global__ void __launch_bounds__(256) scan_offsets(const int* __restrict__ cnti,
                                                    int* __restrict__ off,
                                                    int* __restrict__ cursor) {
    __shared__ int ls[256];
    const int t = threadIdx.x;
    const int lo = t * 196;
    const int hi = min(lo + 196, N_NODES);
    int sum = 0;
    for (int i = lo; i < hi; i++) sum += cnti[i];
    ls[t] = sum;
    __syncthreads();
    for (int d = 1; d < 256; d <<= 1) {
        int v = (t >= d) ? ls[t - d] : 0;
        __syncthreads();
        ls[t] += v;
        __syncthreads();
    }
    int run = (t == 0) ? 0 : ls[t - 1];
    for (int i = lo; i < hi; i++) {
        off[i] = run;
        cursor[i] = run;
        run += cnti[i];
    }
    if (t == 255) off[N_NODES] = run;   // == N_EDGES
}

__global__ void build_perm(const int* __restrict__ eidx, const int* __restrict__ flags,
                           int* __restrict__ cursor, int* __restrict__ perm) {
    int e = blockIdx.x * 256 + threadIdx.x;
    int pos = atomicAdd(&cursor[load_r(eidx, flags[0], e)], 1);
    perm[pos] = e;
}

// ---- encoder MLP 6->18->18->16 (lrelu each) ----
// B16H=0: e0 (f32) -> slot 4 of out. B16H=1: e0 (bf16) -> e0b ring buffer.
template <int B16H>
__global__ void __launch_bounds__(256) encoder(const float* __restrict__ ea,
                                               const float* __restrict__ wsW,
                                               float* __restrict__ outbase,
                                               unsigned short* __restrict__ e0b) {
    int e = blockIdx.x * 256 + threadIdx.x;  // E % 256 == 0
    const float* ap = ea + (size_t)e * 6;
    float a[6];
#pragma unroll
    for (int k = 0; k < 6; k++) a[k] = ap[k];

    float h1[18];
#pragma unroll
    for (int j = 0; j < 18; j++) h1[j] = wsW[O_ENCB0 + j];
#pragma unroll
    for (int k = 0; k < 6; k++) {
        float v = a[k];
#pragma unroll
        for (int j = 0; j < 18; j++) h1[j] = fmaf(v, wsW[O_ENCW0 + k * 18 + j], h1[j]);
    }
#pragma unroll
    for (int j = 0; j < 18; j++) h1[j] = lrelu(h1[j]);

    float h2[18];
#pragma unroll
    for (int j = 0; j < 18; j++) h2[j] = wsW[O_ENCB1 + j];
#pragma unroll
    for (int k = 0; k < 18; k++) {
        float v = h1[k];
#pragma unroll
        for (int j = 0; j < 18; j++) h2[j] = fmaf(v, wsW[O_ENCW1 + k * 18 + j], h2[j]);
    }
#pragma unroll
    for (int j = 0; j < 18; j++) h2[j] = lrelu(h2[j]);

    float o[16];
#pragma unroll
    for (int j = 0; j < 16; j++) o[j] = wsW[O_ENCB2 + j];
#pragma unroll
    for (int k = 0; k < 18; k++) {
        float v = h2[k];
#pragma unroll
        for (int j = 0; j < 16; j++) o[j] = fmaf(v, wsW[O_ENCW2 + k * 16 + j], o[j]);
    }
    if (B16H) {
        unsigned int pw[8];
#pragma unroll
        for (int q = 0; q < 8; q++) {
            float a0 = lrelu(o[2 * q]), a1 = lrelu(o[2 * q + 1]);
            pw[q] = (unsigned int)f2bf(a0) | ((unsigned int)f2bf(a1) << 16);
        }
        uint4* ow = (uint4*)(e0b + (size_t)e * 16);
        ow[0] = make_uint4(pw[0], pw[1], pw[2], pw[3]);
        ow[1] = make_uint4(pw[4], pw[5], pw[6], pw[7]);
    } else {
        float4* ow = (float4*)(outbase + (size_t)4 * N_EDGES * 16 + (size_t)e * 16);
#pragma unroll
        for (int q = 0; q < 4; q++)
            ow[q] = make_float4(lrelu(o[4 * q]), lrelu(o[4 * q + 1]),
                                lrelu(o[4 * q + 2]), lrelu(o[4 * q + 3]));
    }
}

// ---- edge update (f32-history fallback; round-12 proven): dual 16-edge groups ----
__global__ void __launch_bounds__(256) edge_mfma(const unsigned short* __restrict__ ncb,
                                                 const float* __restrict__ outb_c,
                                                 int slot_e0, int slot_prev, int slot_cur,
                                                 const int* __restrict__ eidx,
                                                 const int* __restrict__ flags,
                                                 const float* __restrict__ wsW,
                                                 const unsigned short* __restrict__ wT,
                                                 float* __restrict__ outb) {
    __shared__ unsigned short act1[4][32 * 104];  // 26.6 KB total
    const int lane = threadIdx.x & 63;
    const int wave = threadIdx.x >> 6;
    const int r16 = lane & 15;
    const int g = lane >> 4;
    const int flag64 = flags[0];
    unsigned short* aw = act1[wave];

    const int ebase = blockIdx.x * 128 + wave * 32;
    const float* e0s = outb_c + (size_t)slot_e0 * N_EDGES * 16;
    const float* eps = outb_c + (size_t)slot_prev * N_EDGES * 16;

#pragma unroll
    for (int u = 0; u < 2; u++) {
        bf16x4 z4 = {0, 0, 0, 0};
        *(bf16x4*)&aw[(u * 16 + r16) * 104 + 80 + g * 4] = z4;
    }

    bf16x8 a[2][5];
#pragma unroll
    for (int u = 0; u < 2; u++) {
        const int el = ebase + u * 16 + r16;
        int r_el, c_el;
        load_rc(eidx, flag64, el, r_el, c_el);
        a[u][0] = *(const bf16x8*)(ncb + (size_t)r_el * 64 + g * 8);
        a[u][1] = *(const bf16x8*)(ncb + (size_t)r_el * 64 + 32 + g * 8);
        a[u][2] = *(const bf16x8*)(ncb + (size_t)c_el * 64 + g * 8);
        a[u][3] = *(const bf16x8*)(ncb + (size_t)c_el * 64 + 32 + g * 8);
        const float* src = (g < 2) ? e0s : eps;
        const float4* p = (const float4*)(src + (size_t)el * 16 + (g & 1) * 8);
        a[u][4] = pack8(p[0], p[1]);
    }

#pragma unroll
    for (int t = 0; t < 5; t++) {
        float bv = wsW[O_EDGEB0 + t * 16 + r16];
        f32x4 acc0 = {bv, bv, bv, bv};
        f32x4 acc1 = {bv, bv, bv, bv};
#pragma unroll
        for (int st = 0; st < 5; st++) {
            bf16x8 b = *(const bf16x8*)(wT + (t * 16 + r16) * 160 + st * 32 + g * 8);
            acc0 = __builtin_amdgcn_mfma_f32_16x16x32_bf16(a[0][st], b, acc0, 0, 0, 0);
            acc1 = __builtin_amdgcn_mfma_f32_16x16x32_bf16(a[1][st], b, acc1, 0, 0, 0);
        }
#pragma unroll
        for (int i = 0; i < 4; i++) {
            aw[(g * 4 + i) * 104 + t * 16 + r16]        = f2bf(lrelu(acc0[i]));
            aw[(16 + g * 4 + i) * 104 + t * 16 + r16]   = f2bf(lrelu(acc1[i]));
        }
    }
    asm volatile("s_waitcnt lgkmcnt(0)" ::: "memory");
    __builtin_amdgcn_sched_barrier(0);

    float bv2 = wsW[O_EDGEB1 + r16];
    f32x4 acc20 = {bv2, bv2, bv2, bv2};
    f32x4 acc21 = {bv2, bv2, bv2, bv2};
#pragma unroll
    for (int st = 0; st < 3; st++) {
        bf16x8 b2 = *(const bf16x8*)(wT + 12800 + r16 * 96 + st * 32 + g * 8);
        bf16x8 a20 = *(const bf16x8*)&aw[r16 * 104 + st * 32 + g * 8];
        bf16x8 a21 = *(const bf16x8*)&aw[(16 + r16) * 104 + st * 32 + g * 8];
        acc20 = __builtin_amdgcn_mfma_f32_16x16x32_bf16(a20, b2, acc20, 0, 0, 0);
        acc21 = __builtin_amdgcn_mfma_f32_16x16x32_bf16(a21, b2, acc21, 0, 0, 0);
    }

    float* oc = outb + (size_t)slot_cur * N_EDGES * 16;
#pragma unroll
    for (int i = 0; i < 4; i++) {
        int eg0 = ebase + g * 4 + i;
        int eg1 = ebase + 16 + g * 4 + i;
        oc[(size_t)eg0 * 16 + r16] = lrelu(acc20[i]);
        oc[(size_t)eg1 * 16 + r16] = lrelu(acc21[i]);
    }
}

// ---- edge update (bf16-history ring): dual groups; e0/prev bf16, cur bf16 + f32 out ----
// WOUT=0 for t=1 (no output slot), 1 for t>=2.
template <int WOUT>
__global__ void __launch_bounds__(256) edge_mfma_b16(const unsigned short* __restrict__ ncb,
                                                     const unsigned short* __restrict__ e0b,
                                                     const unsigned short* __restrict__ prevb,
                                                     unsigned short* __restrict__ curb,
                                                     const int* __restrict__ eidx,
                                                     const int* __restrict__ flags,
                                                     const float* __restrict__ wsW,
                                                     const unsigned short* __restrict__ wT,
                                                     float* __restrict__ oc) {
    __shared__ unsigned short act1[4][32 * 104];  // 26.6 KB total
    const int lane = threadIdx.x & 63;
    const int wave = threadIdx.x >> 6;
    const int r16 = lane & 15;
    const int g = lane >> 4;
    const int flag64 = flags[0];
    unsigned short* aw = act1[wave];

    const int ebase = blockIdx.x * 128 + wave * 32;

#pragma unroll
    for (int u = 0; u < 2; u++) {
        bf16x4 z4 = {0, 0, 0, 0};
        *(bf16x4*)&aw[(u * 16 + r16) * 104 + 80 + g * 4] = z4;
    }

    bf16x8 a[2][5];
#pragma unroll
    for (int u = 0; u < 2; u++) {
        const int el = ebase + u * 16 + r16;
        int r_el, c_el;
        load_rc(eidx, flag64, el, r_el, c_el);
        a[u][0] = *(const bf16x8*)(ncb + (size_t)r_el * 64 + g * 8);
        a[u][1] = *(const bf16x8*)(ncb + (size_t)r_el * 64 + 32 + g * 8);
        a[u][2] = *(const bf16x8*)(ncb + (size_t)c_el * 64 + g * 8);
        a[u][3] = *(const bf16x8*)(ncb + (size_t)c_el * 64 + 32 + g * 8);
        const unsigned short* src = (g < 2) ? e0b : prevb;
        a[u][4] = *(const bf16x8*)(src + (size_t)el * 16 + (g & 1) * 8);
    }

#pragma unroll
    for (int t = 0; t < 5; t++) {
        float bv = wsW[O_EDGEB0 + t * 16 + r16];
        f32x4 acc0 = {bv, bv, bv, bv};
        f32x4 acc1 = {bv, bv, bv, bv};
#pragma unroll
        for (int st = 0; st < 5; st++) {
            bf16x8 b = *(const bf16x8*)(wT + (t * 16 + r16) * 160 + st * 32 + g * 8);
            acc0 = __builtin_amdgcn_mfma_f32_16x16x32_bf16(a[0][st], b, acc0, 0, 0, 0);
            acc1 = __builtin_amdgcn_mfma_f32_16x16x32_bf16(a[1][st], b, acc1, 0, 0, 0);
        }
#pragma unroll
        for (int i = 0; i < 4; i++) {
            aw[(g * 4 + i) * 104 + t * 16 + r16]        = f2bf(lrelu(acc0[i]));
            aw[(16 + g * 4 + i) * 104 + t * 16 + r16]   = f2bf(lrelu(acc1[i]));
        }
    }
    asm volatile("s_waitcnt lgkmcnt(0)" ::: "memory");
    __builtin_amdgcn_sched_barrier(0);

    float bv2 = wsW[O_EDGEB1 + r16];
    f32x4 acc20 = {bv2, bv2, bv2, bv2};
    f32x4 acc21 = {bv2, bv2, bv2, bv2};
#pragma unroll
    for (int st = 0; st < 3; st++) {
        bf16x8 b2 = *(const bf16x8*)(wT + 12800 + r16 * 96 + st * 32 + g * 8);
        bf16x8 a20 = *(const bf16x8*)&aw[r16 * 104 + st * 32 + g * 8];
        bf16x8 a21 = *(const bf16x8*)&aw[(16 + r16) * 104 + st * 32 + g * 8];
        acc20 = __builtin_amdgcn_mfma_f32_16x16x32_bf16(a20, b2, acc20, 0, 0, 0);
        acc21 = __builtin_amdgcn_mfma_f32_16x16x32_bf16(a21, b2, acc21, 0, 0, 0);
    }

#pragma unroll
    for (int i = 0; i < 4; i++) {
        int eg0 = ebase + g * 4 + i;
        int eg1 = ebase + 16 + g * 4 + i;
        float v0 = lrelu(acc20[i]);
        float v1 = lrelu(acc21[i]);
        curb[(size_t)eg0 * 16 + r16] = f2bf(v0);
        curb[(size_t)eg1 * 16 + r16] = f2bf(v1);
        if (WOUT) {
            oc[(size_t)eg0 * 16 + r16] = v0;
            oc[(size_t)eg1 * 16 + r16] = v1;
        }
    }
}

// ---- gather-mean (f32 source, fallback) ----
__global__ void __launch_bounds__(256) gather_mean(const int* __restrict__ off,
                                                   const int* __restrict__ perm,
                                                   const float* __restrict__ ecur,
                                                   float* __restrict__ msg) {
    const int wave = threadIdx.x >> 6;
    const int lane = threadIdx.x & 63;
    const int i = blockIdx.x * 4 + wave;   // 12500 * 4 = 50000 exactly
    const int c = lane & 15;
    const int sub = lane >> 4;
    const int p0 = off[i], p1 = off[i + 1];
    float sum = 0.f;
    for (int p = p0 + sub; p < p1; p += 4)
        sum += ecur[(size_t)perm[p] * 16 + c];
    sum += __shfl_xor(sum, 16, 64);
    sum += __shfl_xor(sum, 32, 64);
    if (lane < 16) {
        float inv = 1.0f / fmaxf((float)(p1 - p0), 1.0f);
        msg[(size_t)i * 16 + c] = sum * inv;
    }
}

// ---- gather-mean (bf16 ring source) ----
__global__ void __launch_bounds__(256) gather_mean_b16(const int* __restrict__ off,
                                                       const int* __restrict__ perm,
                                                       const unsigned short* __restrict__ ecurb,
                                                       float* __restrict__ msg) {
    const int wave = threadIdx.x >> 6;
    const int lane = threadIdx.x & 63;
    const int i = blockIdx.x * 4 + wave;
    const int c = lane & 15;
    const int sub = lane >> 4;
    const int p0 = off[i], p1 = off[i + 1];
    float sum = 0.f;
    for (int p = p0 + sub; p < p1; p += 4)
        sum += bf2f((unsigned int)ecurb[(size_t)perm[p] * 16 + c]);
    sum += __shfl_xor(sum, 16, 64);
    sum += __shfl_xor(sum, 32, 64);
    if (lane < 16) {
        float inv = 1.0f / fmaxf((float)(p1 - p0), 1.0f);
        msg[(size_t)i * 16 + c] = sum * inv;
    }
}

// ---- node MLP: nh=[nc(bf16->f32), msg] (80) -> 56 (relu) -> 32 (relu) ----
__global__ void __launch_bounds__(64) node_mlp(const float* __restrict__ msg,
                                               unsigned short* __restrict__ ncb,
                                               const float* __restrict__ wsW) {
    __shared__ float sl[64 * 81];
    const int l = threadIdx.x;
    const int i = blockIdx.x * 64 + l;
    if (i >= N_NODES) return;
    const float* W0 = wsW + O_NODEW0;
    const float* b0 = wsW + O_NODEB0;
    const float* W1 = wsW + O_NODEW1;
    const float* b1 = wsW + O_NODEB1;

    const uint4* ncp = (const uint4*)(ncb + (size_t)i * 64);
#pragma unroll
    for (int q = 0; q < 8; q++) {
        uint4 u = ncp[q];
        int base = l * 81 + 8 * q;
        sl[base + 0] = bf2f(u.x & 0xffffu); sl[base + 1] = bf2f(u.x >> 16);
        sl[base + 2] = bf2f(u.y & 0xffffu); sl[base + 3] = bf2f(u.y >> 16);
        sl[base + 4] = bf2f(u.z & 0xffffu); sl[base + 5] = bf2f(u.z >> 16);
        sl[base + 6] = bf2f(u.w & 0xffffu); sl[base + 7] = bf2f(u.w >> 16);
    }
    const float4* mp = (const float4*)(msg + (size_t)i * 16);
#pragma unroll
    for (int q = 0; q < 4; q++) {
        float4 v = mp[q];
        int base = l * 81 + 64 + 4 * q;
        sl[base] = v.x; sl[base + 1] = v.y; sl[base + 2] = v.z; sl[base + 3] = v.w;
    }

    float h[56];
#pragma unroll
    for (int q = 0; q < 14; q++) {
        float4 b = ((const float4*)b0)[q];
        h[4 * q] = b.x; h[4 * q + 1] = b.y; h[4 * q + 2] = b.z; h[4 * q + 3] = b.w;
    }
    for (int k = 0; k < 80; k++) {
        float v = sl[l * 81 + k];
        const float4* w = (const float4*)(W0 + k * 56);
#pragma unroll
        for (int q = 0; q < 14; q++) {
            float4 wv = w[q];
            h[4 * q]     = fmaf(v, wv.x, h[4 * q]);
            h[4 * q + 1] = fmaf(v, wv.y, h[4 * q + 1]);
            h[4 * q + 2] = fmaf(v, wv.z, h[4 * q + 2]);
            h[4 * q + 3] = fmaf(v, wv.w, h[4 * q + 3]);
        }
    }
#pragma unroll
    for (int j = 0; j < 56; j++) sl[l * 81 + j] = fmaxf(h[j], 0.f);

    float o[32];
#pragma unroll
    for (int q = 0; q < 8; q++) {
        float4 b = ((const float4*)b1)[q];
        o[4 * q] = b.x; o[4 * q + 1] = b.y; o[4 * q + 2] = b.z; o[4 * q + 3] = b.w;
    }
    for (int j = 0; j < 56; j++) {
        float v = sl[l * 81 + j];
        const float4* w = (const float4*)(W1 + j * 32);
#pragma unroll
        for (int q = 0; q < 8; q++) {
            float4 wv = w[q];
            o[4 * q]     = fmaf(v, wv.x, o[4 * q]);
            o[4 * q + 1] = fmaf(v, wv.y, o[4 * q + 1]);
            o[4 * q + 2] = fmaf(v, wv.z, o[4 * q + 2]);
            o[4 * q + 3] = fmaf(v, wv.w, o[4 * q + 3]);
        }
    }
    // write n half back as bf16
    uint4* nout = (uint4*)(ncb + (size_t)i * 64 + 32);
#pragma unroll
    for (int q = 0; q < 4; q++) {
        unsigned int w0 = (unsigned int)f2bf(fmaxf(o[8 * q + 0], 0.f)) |
                          ((unsigned int)f2bf(fmaxf(o[8 * q + 1], 0.f)) << 16);
        unsigned int w1 = (unsigned int)f2bf(fmaxf(o[8 * q + 2], 0.f)) |
                          ((unsigned int)f2bf(fmaxf(o[8 * q + 3], 0.f)) << 16);
        unsigned int w2 = (unsigned int)f2bf(fmaxf(o[8 * q + 4], 0.f)) |
                          ((unsigned int)f2bf(fmaxf(o[8 * q + 5], 0.f)) << 16);
        unsigned int w3 = (unsigned int)f2bf(fmaxf(o[8 * q + 6], 0.f)) |
                          ((unsigned int)f2bf(fmaxf(o[8 * q + 7], 0.f)) << 16);
        nout[q] = make_uint4(w0, w1, w2, w3);
    }
}

extern "C" void kernel_launch(void* const* d_in, const int* in_sizes, int n_in,
                              void* d_out, int out_size, void* d_ws, size_t ws_size,
                              hipStream_t stream) {
    (void)in_sizes; (void)n_in; (void)out_size;
    const float* x  = (const float*)d_in[0];
    const int* eidx = (const int*)d_in[1];
    const float* ea = (const float*)d_in[2];
    float* out = (float*)d_out;   // f32 output: 5 slots x E x 16

    // d_ws layout (byte offsets):
    //   wsW @0 (85232) | flags @85232 (16) | cnti @85248 (200000) | off @285248 (200016)
    //   cursor @485264 (200000) | perm @685264 (6400000) | ncb @7085264 (6400000, u16)
    //   wT @13485264 (28672, u16) | msg @13513936 (3200000, f32)
    //   [big-ws only] e0b @16714240 | rb0 | rb1 (each 51,200,000 B, bf16 E x 16)
    char* wsb = (char*)d_ws;
    float* wsW  = (float*)(wsb + 0);
    int* flags  = (int*)(wsb + 85232);
    int* cnti   = (int*)(wsb + 85248);
    int* off    = (int*)(wsb + 285248);
    int* cursor = (int*)(wsb + 485264);
    int* perm   = (int*)(wsb + 685264);
    unsigned short* ncb = (unsigned short*)(wsb + 7085264);
    unsigned short* wT  = (unsigned short*)(wsb + 13485264);
    float* msg  = (float*)(wsb + 13513936);
    const size_t WS_BASE = 16713936ull;
    unsigned short* e0b = (unsigned short*)(wsb + 16714240);
    unsigned short* rb0 = e0b + (size_t)N_EDGES * 16;
    unsigned short* rb1 = rb0 + (size_t)N_EDGES * 16;
    const size_t WS_BIG = 16714240ull + 3ull * 51200000ull;   // ~170.3 MB
    if (ws_size < WS_BASE) return;  // refuse to corrupt memory
    const bool big = (ws_size >= WS_BIG);

    WPack P;
    static const int offs[15] = {0, 108, 126, 450, 468, 756, 772, 13572, 13652,
                                 14932, 14948, 19428, 19484, 21276, 21308};
    for (int a = 0; a < 14; a++) P.p[a] = (const float*)d_in[3 + a];
    for (int a = 0; a < 15; a++) P.off[a] = offs[a];

    detect_flags<<<1, 64, 0, stream>>>(eidx, flags);
    copy_w<<<14, 256, 0, stream>>>(P, wsW);
    build_wT<<<56, 256, 0, stream>>>((const float*)d_in[9], (const float*)d_in[11], wT);
    init_nodes<<<196, 256, 0, stream>>>(x, ncb, cnti);
    count_edges<<<N_EDGES / 256, 256, 0, stream>>>(eidx, flags, cnti);
    scan_offsets<<<1, 256, 0, stream>>>(cnti, off, cursor);
    build_perm<<<N_EDGES / 256, 256, 0, stream>>>(eidx, flags, cursor, perm);

    if (big) {
        // bf16 e-history ring in ws; d_out slots written exactly once (t>=2 -> slot t-2)
        encoder<1><<<N_EDGES / 256, 256, 0, stream>>>(ea, wsW, out, e0b);
        unsigned short* rings[2] = {rb0, rb1};
        for (int t = 1; t <= 6; t++) {
            unsigned short* prevb = (t == 1) ? e0b : rings[(t - 1) & 1];
            unsigned short* curb  = rings[t & 1];
            if (t == 1)
                edge_mfma_b16<0><<<N_EDGES / 128, 256, 0, stream>>>(
                    ncb, e0b, prevb, curb, eidx, flags, wsW, wT, out);
            else
                edge_mfma_b16<1><<<N_EDGES / 128, 256, 0, stream>>>(
                    ncb, e0b, prevb, curb, eidx, flags, wsW, wT,
                    out + (size_t)(t - 2) * N_EDGES * 16);
            if (t < 6) {
                gather_mean_b16<<<12500, 256, 0, stream>>>(off, perm, curb, msg);
                node_mlp<<<782, 64, 0, stream>>>(msg, ncb, wsW);
            }
        }
    } else {
        // f32 history in d_out slot ring (round-12 proven path)
        encoder<0><<<N_EDGES / 256, 256, 0, stream>>>(ea, wsW, out, nullptr);
        const int prevs[6] = {4, 0, 0, 1, 2, 3};
        const int curs[6]  = {0, 0, 1, 2, 3, 4};
        for (int t = 1; t <= 6; t++) {
            edge_mfma<<<N_EDGES / 128, 256, 0, stream>>>(ncb, out, 4, prevs[t - 1],
                                                         curs[t - 1], eidx, flags, wsW,
                                                         wT, out);
            if (t < 6) {
                gather_mean<<<12500, 256, 0, stream>>>(
                    off, perm, out + (size_t)curs[t - 1] * N_EDGES * 16, msg);
                node_mlp<<<782, 64, 0, stream>>>(msg, ncb, wsW);
            }
        }
    }
}

// Round 15
// 1604.163 us; speedup vs baseline: 1.1999x; 1.0996x over previous
//
#include <hip/hip_runtime.h>

#define N_NODES 50000
#define N_EDGES 1600000

// weight offsets (floats) inside the weights region of d_ws
#define O_ENCW0 0
#define O_ENCB0 108
#define O_ENCW1 126
#define O_ENCB1 450
#define O_ENCW2 468
#define O_ENCB2 756
#define O_EDGEW0 772
#define O_EDGEB0 13572
#define O_EDGEW1 13652
#define O_EDGEB1 14932
#define O_NODEW0 14948
#define O_NODEB0 19428
#define O_NODEW1 19484
#define O_NODEB1 21276
#define W_TOTAL 21308

typedef __attribute__((ext_vector_type(8))) short bf16x8;
typedef __attribute__((ext_vector_type(4))) short bf16x4;
typedef __attribute__((ext_vector_type(4))) float f32x4;

__device__ __forceinline__ float bf2f(unsigned int u) {
    return __uint_as_float(u << 16);
}
__device__ __forceinline__ unsigned short f2bf(float f) {
    unsigned int u = __float_as_uint(f);
    u += 0x7fffu + ((u >> 16) & 1u);   // RNE (finite values only here)
    return (unsigned short)(u >> 16);
}
__device__ __forceinline__ float lrelu(float x) { return x > 0.f ? x : 0.01f * x; }

__device__ __forceinline__ bf16x8 pack8(float4 a, float4 b) {
    bf16x8 r;
    r[0] = (short)f2bf(a.x); r[1] = (short)f2bf(a.y);
    r[2] = (short)f2bf(a.z); r[3] = (short)f2bf(a.w);
    r[4] = (short)f2bf(b.x); r[5] = (short)f2bf(b.y);
    r[6] = (short)f2bf(b.z); r[7] = (short)f2bf(b.w);
    return r;
}

struct WPack {
    const float* p[14];
    int off[15];
};

// ---- detect flag: edge_index is int64 (high words of first 64 entries all zero) ----
__global__ void detect_flags(const int* __restrict__ eidx, int* __restrict__ flags) {
    int t = threadIdx.x;  // 64 threads
    int v = eidx[2 * t + 1];
    unsigned long long bi = __ballot(v != 0);
    if (t == 0) flags[0] = (bi == 0ull) ? 1 : 0;
}

__device__ __forceinline__ void load_rc(const int* eidx, int flag64, int e, int& r, int& c) {
    if (flag64) {
        const long long* e64 = (const long long*)eidx;
        r = (int)e64[e];
        c = (int)e64[N_EDGES + e];
    } else {
        r = eidx[e];
        c = eidx[N_EDGES + e];
    }
}
__device__ __forceinline__ int load_r(const int* eidx, int flag64, int e) {
    return flag64 ? (int)((const long long*)eidx)[e] : eidx[e];
}

// ---- copy all f32 weight/bias arrays into contiguous ws region ----
__global__ void copy_w(WPack P, float* __restrict__ dst) {
    int a = blockIdx.x;
    const float* s = P.p[a];
    int n = P.off[a + 1] - P.off[a];
    float* d = dst + P.off[a];
    for (int i = threadIdx.x; i < n; i += 256) d[i] = s[i];
}

// ---- build transposed bf16 weights for MFMA B-fragments ----
__global__ void build_wT(const float* __restrict__ w0,
                         const float* __restrict__ w1,
                         unsigned short* __restrict__ wT) {
    int t = blockIdx.x * 256 + threadIdx.x;  // 56 * 256 = 14336
    if (t < 12800) {
        int col = t / 160, k = t % 160;
        wT[t] = f2bf(w0[k * 80 + col]);
    } else if (t < 14336) {
        int u = t - 12800;
        int col = u / 96, k = u % 96;
        wT[t] = (k < 80) ? f2bf(w1[k * 16 + col]) : (unsigned short)0;
    }
}

// ---- n0 = lrelu(x) (f32 in) stored bf16; ncb = [n0, n0]; zero cnti ----
__global__ void __launch_bounds__(256) init_nodes(const float* __restrict__ x,
                                                  unsigned short* __restrict__ ncb,
                                                  int* __restrict__ cnti) {
    int i = blockIdx.x * 256 + threadIdx.x;
    if (i >= N_NODES) return;
    const float4* xin = (const float4*)(x + (size_t)i * 32);  // 8 float4
    uint4* np = (uint4*)(ncb + (size_t)i * 64);
#pragma unroll
    for (int q = 0; q < 4; q++) {
        float4 a = xin[2 * q];
        float4 b = xin[2 * q + 1];
        unsigned int w0 = (unsigned int)f2bf(lrelu(a.x)) | ((unsigned int)f2bf(lrelu(a.y)) << 16);
        unsigned int w1 = (unsigned int)f2bf(lrelu(a.z)) | ((unsigned int)f2bf(lrelu(a.w)) << 16);
        unsigned int w2 = (unsigned int)f2bf(lrelu(b.x)) | ((unsigned int)f2bf(lrelu(b.y)) << 16);
        unsigned int w3 = (unsigned int)f2bf(lrelu(b.z)) | ((unsigned int)f2bf(lrelu(b.w)) << 16);
        uint4 o = make_uint4(w0, w1, w2, w3);
        np[q] = o;       // n0 half (bf16)
        np[4 + q] = o;   // n half (n == n0 initially)
    }
    cnti[i] = 0;
}

// ---- CSR build: count, scan, bucket ----
__global__ void count_edges(const int* __restrict__ eidx, const int* __restrict__ flags,
                            int* __restrict__ cnti) {
    int e = blockIdx.x * 256 + threadIdx.x;
    atomicAdd(&cnti[load_r(eidx, flags[0], e)], 1);
}

__global__ void __launch_bounds__(256) scan_offsets(const int* __restrict__ cnti,
                                                    int* __restrict__ off,
                                                    int* __restrict__ cursor) {
    __shared__ int ls[256];
    const int t = threadIdx.x;
    const int lo = t * 196;
    const int hi = min(lo + 196, N_NODES);
    int sum = 0;
    for (int i = lo; i < hi; i++) sum += cnti[i];
    ls[t] = sum;
    __syncthreads();
    for (int d = 1; d < 256; d <<= 1) {
        int v = (t >= d) ? ls[t - d] : 0;
        __syncthreads();
        ls[t] += v;
        __syncthreads();
    }
    int run = (t == 0) ? 0 : ls[t - 1];
    for (int i = lo; i < hi; i++) {
        off[i] = run;
        cursor[i] = run;
        run += cnti[i];
    }
    if (t == 255) off[N_NODES] = run;   // == N_EDGES
}

// EXT=1 additionally records rcp[pos]=(row,col) and pose[e]=pos for the perm path
template <int EXT>
__global__ void build_perm(const int* __restrict__ eidx, const int* __restrict__ flags,
                           int* __restrict__ cursor, int* __restrict__ perm,
                           int2* __restrict__ rcp, int* __restrict__ pose) {
    int e = blockIdx.x * 256 + threadIdx.x;
    int r, c;
    load_rc(eidx, flags[0], e, r, c);
    int pos = atomicAdd(&cursor[r], 1);
    perm[pos] = e;
    if (EXT) {
        rcp[pos] = make_int2(r, c);
        pose[e] = pos;
    }
}

// ---- encoder MLP 6->18->18->16 (lrelu each) ----
// MODE 0: e0 f32 -> slot4 of out; MODE 1: e0 bf16 -> e0b[e]; MODE 2: bf16 -> e0b[pose[e]]
template <int MODE>
__global__ void __launch_bounds__(256) encoder(const float* __restrict__ ea,
                                               const float* __restrict__ wsW,
                                               float* __restrict__ outbase,
                                               unsigned short* __restrict__ e0b,
                                               const int* __restrict__ pose) {
    int e = blockIdx.x * 256 + threadIdx.x;  // E % 256 == 0
    const float* ap = ea + (size_t)e * 6;
    float a[6];
#pragma unroll
    for (int k = 0; k < 6; k++) a[k] = ap[k];

    float h1[18];
#pragma unroll
    for (int j = 0; j < 18; j++) h1[j] = wsW[O_ENCB0 + j];
#pragma unroll
    for (int k = 0; k < 6; k++) {
        float v = a[k];
#pragma unroll
        for (int j = 0; j < 18; j++) h1[j] = fmaf(v, wsW[O_ENCW0 + k * 18 + j], h1[j]);
    }
#pragma unroll
    for (int j = 0; j < 18; j++) h1[j] = lrelu(h1[j]);

    float h2[18];
#pragma unroll
    for (int j = 0; j < 18; j++) h2[j] = wsW[O_ENCB1 + j];
#pragma unroll
    for (int k = 0; k < 18; k++) {
        float v = h1[k];
#pragma unroll
        for (int j = 0; j < 18; j++) h2[j] = fmaf(v, wsW[O_ENCW1 + k * 18 + j], h2[j]);
    }
#pragma unroll
    for (int j = 0; j < 18; j++) h2[j] = lrelu(h2[j]);

    float o[16];
#pragma unroll
    for (int j = 0; j < 16; j++) o[j] = wsW[O_ENCB2 + j];
#pragma unroll
    for (int k = 0; k < 18; k++) {
        float v = h2[k];
#pragma unroll
        for (int j = 0; j < 16; j++) o[j] = fmaf(v, wsW[O_ENCW2 + k * 16 + j], o[j]);
    }
    if (MODE == 0) {
        float4* ow = (float4*)(outbase + (size_t)4 * N_EDGES * 16 + (size_t)e * 16);
#pragma unroll
        for (int q = 0; q < 4; q++)
            ow[q] = make_float4(lrelu(o[4 * q]), lrelu(o[4 * q + 1]),
                                lrelu(o[4 * q + 2]), lrelu(o[4 * q + 3]));
    } else {
        unsigned int pw[8];
#pragma unroll
        for (int q = 0; q < 8; q++) {
            float a0 = lrelu(o[2 * q]), a1 = lrelu(o[2 * q + 1]);
            pw[q] = (unsigned int)f2bf(a0) | ((unsigned int)f2bf(a1) << 16);
        }
        size_t pos = (MODE == 2) ? (size_t)pose[e] : (size_t)e;
        uint4* ow = (uint4*)(e0b + pos * 16);
        ow[0] = make_uint4(pw[0], pw[1], pw[2], pw[3]);
        ow[1] = make_uint4(pw[4], pw[5], pw[6], pw[7]);
    }
}

// ---- edge update core (dual 16-edge groups, both layers MFMA) ----
// MFMA 16x16x32 frags (m97/m89-verified): A row=lane&15, k=st*32+(lane>>4)*8+j;
// B col=lane&15, same k; D col=lane&15, row=4*(lane>>4)+reg.
// act1 per-wave bf16 [32][104]; lgkmcnt+sched_barrier fences (rule #18), no barrier.

// (A) f32-history fallback (round-12 proven)
__global__ void __launch_bounds__(256) edge_mfma(const unsigned short* __restrict__ ncb,
                                                 const float* __restrict__ outb_c,
                                                 int slot_e0, int slot_prev, int slot_cur,
                                                 const int* __restrict__ eidx,
                                                 const int* __restrict__ flags,
                                                 const float* __restrict__ wsW,
                                                 const unsigned short* __restrict__ wT,
                                                 float* __restrict__ outb) {
    __shared__ unsigned short act1[4][32 * 104];
    const int lane = threadIdx.x & 63;
    const int wave = threadIdx.x >> 6;
    const int r16 = lane & 15;
    const int g = lane >> 4;
    const int flag64 = flags[0];
    unsigned short* aw = act1[wave];

    const int ebase = blockIdx.x * 128 + wave * 32;
    const float* e0s = outb_c + (size_t)slot_e0 * N_EDGES * 16;
    const float* eps = outb_c + (size_t)slot_prev * N_EDGES * 16;

#pragma unroll
    for (int u = 0; u < 2; u++) {
        bf16x4 z4 = {0, 0, 0, 0};
        *(bf16x4*)&aw[(u * 16 + r16) * 104 + 80 + g * 4] = z4;
    }

    bf16x8 a[2][5];
#pragma unroll
    for (int u = 0; u < 2; u++) {
        const int el = ebase + u * 16 + r16;
        int r_el, c_el;
        load_rc(eidx, flag64, el, r_el, c_el);
        a[u][0] = *(const bf16x8*)(ncb + (size_t)r_el * 64 + g * 8);
        a[u][1] = *(const bf16x8*)(ncb + (size_t)r_el * 64 + 32 + g * 8);
        a[u][2] = *(const bf16x8*)(ncb + (size_t)c_el * 64 + g * 8);
        a[u][3] = *(const bf16x8*)(ncb + (size_t)c_el * 64 + 32 + g * 8);
        const float* src = (g < 2) ? e0s : eps;
        const float4* p = (const float4*)(src + (size_t)el * 16 + (g & 1) * 8);
        a[u][4] = pack8(p[0], p[1]);
    }

#pragma unroll
    for (int t = 0; t < 5; t++) {
        float bv = wsW[O_EDGEB0 + t * 16 + r16];
        f32x4 acc0 = {bv, bv, bv, bv};
        f32x4 acc1 = {bv, bv, bv, bv};
#pragma unroll
        for (int st = 0; st < 5; st++) {
            bf16x8 b = *(const bf16x8*)(wT + (t * 16 + r16) * 160 + st * 32 + g * 8);
            acc0 = __builtin_amdgcn_mfma_f32_16x16x32_bf16(a[0][st], b, acc0, 0, 0, 0);
            acc1 = __builtin_amdgcn_mfma_f32_16x16x32_bf16(a[1][st], b, acc1, 0, 0, 0);
        }
#pragma unroll
        for (int i = 0; i < 4; i++) {
            aw[(g * 4 + i) * 104 + t * 16 + r16]      = f2bf(lrelu(acc0[i]));
            aw[(16 + g * 4 + i) * 104 + t * 16 + r16] = f2bf(lrelu(acc1[i]));
        }
    }
    asm volatile("s_waitcnt lgkmcnt(0)" ::: "memory");
    __builtin_amdgcn_sched_barrier(0);

    float bv2 = wsW[O_EDGEB1 + r16];
    f32x4 acc20 = {bv2, bv2, bv2, bv2};
    f32x4 acc21 = {bv2, bv2, bv2, bv2};
#pragma unroll
    for (int st = 0; st < 3; st++) {
        bf16x8 b2 = *(const bf16x8*)(wT + 12800 + r16 * 96 + st * 32 + g * 8);
        bf16x8 a20 = *(const bf16x8*)&aw[r16 * 104 + st * 32 + g * 8];
        bf16x8 a21 = *(const bf16x8*)&aw[(16 + r16) * 104 + st * 32 + g * 8];
        acc20 = __builtin_amdgcn_mfma_f32_16x16x32_bf16(a20, b2, acc20, 0, 0, 0);
        acc21 = __builtin_amdgcn_mfma_f32_16x16x32_bf16(a21, b2, acc21, 0, 0, 0);
    }

    float* oc = outb + (size_t)slot_cur * N_EDGES * 16;
#pragma unroll
    for (int i = 0; i < 4; i++) {
        int eg0 = ebase + g * 4 + i;
        int eg1 = ebase + 16 + g * 4 + i;
        oc[(size_t)eg0 * 16 + r16] = lrelu(acc20[i]);
        oc[(size_t)eg1 * 16 + r16] = lrelu(acc21[i]);
    }
}

// (B) bf16-history, edge-id order (round-14 proven)
template <int WOUT>
__global__ void __launch_bounds__(256) edge_mfma_b16(const unsigned short* __restrict__ ncb,
                                                     const unsigned short* __restrict__ e0b,
                                                     const unsigned short* __restrict__ prevb,
                                                     unsigned short* __restrict__ curb,
                                                     const int* __restrict__ eidx,
                                                     const int* __restrict__ flags,
                                                     const float* __restrict__ wsW,
                                                     const unsigned short* __restrict__ wT,
                                                     float* __restrict__ oc) {
    __shared__ unsigned short act1[4][32 * 104];
    const int lane = threadIdx.x & 63;
    const int wave = threadIdx.x >> 6;
    const int r16 = lane & 15;
    const int g = lane >> 4;
    const int flag64 = flags[0];
    unsigned short* aw = act1[wave];

    const int ebase = blockIdx.x * 128 + wave * 32;

#pragma unroll
    for (int u = 0; u < 2; u++) {
        bf16x4 z4 = {0, 0, 0, 0};
        *(bf16x4*)&aw[(u * 16 + r16) * 104 + 80 + g * 4] = z4;
    }

    bf16x8 a[2][5];
#pragma unroll
    for (int u = 0; u < 2; u++) {
        const int el = ebase + u * 16 + r16;
        int r_el, c_el;
        load_rc(eidx, flag64, el, r_el, c_el);
        a[u][0] = *(const bf16x8*)(ncb + (size_t)r_el * 64 + g * 8);
        a[u][1] = *(const bf16x8*)(ncb + (size_t)r_el * 64 + 32 + g * 8);
        a[u][2] = *(const bf16x8*)(ncb + (size_t)c_el * 64 + g * 8);
        a[u][3] = *(const bf16x8*)(ncb + (size_t)c_el * 64 + 32 + g * 8);
        const unsigned short* src = (g < 2) ? e0b : prevb;
        a[u][4] = *(const bf16x8*)(src + (size_t)el * 16 + (g & 1) * 8);
    }

#pragma unroll
    for (int t = 0; t < 5; t++) {
        float bv = wsW[O_EDGEB0 + t * 16 + r16];
        f32x4 acc0 = {bv, bv, bv, bv};
        f32x4 acc1 = {bv, bv, bv, bv};
#pragma unroll
        for (int st = 0; st < 5; st++) {
            bf16x8 b = *(const bf16x8*)(wT + (t * 16 + r16) * 160 + st * 32 + g * 8);
            acc0 = __builtin_amdgcn_mfma_f32_16x16x32_bf16(a[0][st], b, acc0, 0, 0, 0);
            acc1 = __builtin_amdgcn_mfma_f32_16x16x32_bf16(a[1][st], b, acc1, 0, 0, 0);
        }
#pragma unroll
        for (int i = 0; i < 4; i++) {
            aw[(g * 4 + i) * 104 + t * 16 + r16]      = f2bf(lrelu(acc0[i]));
            aw[(16 + g * 4 + i) * 104 + t * 16 + r16] = f2bf(lrelu(acc1[i]));
        }
    }
    asm volatile("s_waitcnt lgkmcnt(0)" ::: "memory");
    __builtin_amdgcn_sched_barrier(0);

    float bv2 = wsW[O_EDGEB1 + r16];
    f32x4 acc20 = {bv2, bv2, bv2, bv2};
    f32x4 acc21 = {bv2, bv2, bv2, bv2};
#pragma unroll
    for (int st = 0; st < 3; st++) {
        bf16x8 b2 = *(const bf16x8*)(wT + 12800 + r16 * 96 + st * 32 + g * 8);
        bf16x8 a20 = *(const bf16x8*)&aw[r16 * 104 + st * 32 + g * 8];
        bf16x8 a21 = *(const bf16x8*)&aw[(16 + r16) * 104 + st * 32 + g * 8];
        acc20 = __builtin_amdgcn_mfma_f32_16x16x32_bf16(a20, b2, acc20, 0, 0, 0);
        acc21 = __builtin_amdgcn_mfma_f32_16x16x32_bf16(a21, b2, acc21, 0, 0, 0);
    }

#pragma unroll
    for (int i = 0; i < 4; i++) {
        int eg0 = ebase + g * 4 + i;
        int eg1 = ebase + 16 + g * 4 + i;
        float v0 = lrelu(acc20[i]);
        float v1 = lrelu(acc21[i]);
        curb[(size_t)eg0 * 16 + r16] = f2bf(v0);
        curb[(size_t)eg1 * 16 + r16] = f2bf(v1);
        if (WOUT) {
            oc[(size_t)eg0 * 16 + r16] = v0;
            oc[(size_t)eg1 * 16 + r16] = v1;
        }
    }
}

// (C) bf16-history, PERM (CSR) order: rcp sequential, history sequential,
// nc[row] gathers clustered; WOUT scatters f32 out via perm.
template <int WOUT>
__global__ void __launch_bounds__(256) edge_mfma_perm(const unsigned short* __restrict__ ncb,
                                                      const unsigned short* __restrict__ e0b,
                                                      const unsigned short* __restrict__ prevb,
                                                      unsigned short* __restrict__ curb,
                                                      const int2* __restrict__ rcp,
                                                      const int* __restrict__ perm,
                                                      const float* __restrict__ wsW,
                                                      const unsigned short* __restrict__ wT,
                                                      float* __restrict__ oc) {
    __shared__ unsigned short act1[4][32 * 104];
    const int lane = threadIdx.x & 63;
    const int wave = threadIdx.x >> 6;
    const int r16 = lane & 15;
    const int g = lane >> 4;
    unsigned short* aw = act1[wave];

    const int pbase = blockIdx.x * 128 + wave * 32;

#pragma unroll
    for (int u = 0; u < 2; u++) {
        bf16x4 z4 = {0, 0, 0, 0};
        *(bf16x4*)&aw[(u * 16 + r16) * 104 + 80 + g * 4] = z4;
    }

    bf16x8 a[2][5];
#pragma unroll
    for (int u = 0; u < 2; u++) {
        const int pl = pbase + u * 16 + r16;
        int2 rc = rcp[pl];                      // sequential 8B
        a[u][0] = *(const bf16x8*)(ncb + (size_t)rc.x * 64 + g * 8);
        a[u][1] = *(const bf16x8*)(ncb + (size_t)rc.x * 64 + 32 + g * 8);
        a[u][2] = *(const bf16x8*)(ncb + (size_t)rc.y * 64 + g * 8);
        a[u][3] = *(const bf16x8*)(ncb + (size_t)rc.y * 64 + 32 + g * 8);
        const unsigned short* src = (g < 2) ? e0b : prevb;
        a[u][4] = *(const bf16x8*)(src + (size_t)pl * 16 + (g & 1) * 8);  // sequential
    }

#pragma unroll
    for (int t = 0; t < 5; t++) {
        float bv = wsW[O_EDGEB0 + t * 16 + r16];
        f32x4 acc0 = {bv, bv, bv, bv};
        f32x4 acc1 = {bv, bv, bv, bv};
#pragma unroll
        for (int st = 0; st < 5; st++) {
            bf16x8 b = *(const bf16x8*)(wT + (t * 16 + r16) * 160 + st * 32 + g * 8);
            acc0 = __builtin_amdgcn_mfma_f32_16x16x32_bf16(a[0][st], b, acc0, 0, 0, 0);
            acc1 = __builtin_amdgcn_mfma_f32_16x16x32_bf16(a[1][st], b, acc1, 0, 0, 0);
        }
#pragma unroll
        for (int i = 0; i < 4; i++) {
            aw[(g * 4 + i) * 104 + t * 16 + r16]      = f2bf(lrelu(acc0[i]));
            aw[(16 + g * 4 + i) * 104 + t * 16 + r16] = f2bf(lrelu(acc1[i]));
        }
    }
    asm volatile("s_waitcnt lgkmcnt(0)" ::: "memory");
    __builtin_amdgcn_sched_barrier(0);

    float bv2 = wsW[O_EDGEB1 + r16];
    f32x4 acc20 = {bv2, bv2, bv2, bv2};
    f32x4 acc21 = {bv2, bv2, bv2, bv2};
#pragma unroll
    for (int st = 0; st < 3; st++) {
        bf16x8 b2 = *(const bf16x8*)(wT + 12800 + r16 * 96 + st * 32 + g * 8);
        bf16x8 a20 = *(const bf16x8*)&aw[r16 * 104 + st * 32 + g * 8];
        bf16x8 a21 = *(const bf16x8*)&aw[(16 + r16) * 104 + st * 32 + g * 8];
        acc20 = __builtin_amdgcn_mfma_f32_16x16x32_bf16(a20, b2, acc20, 0, 0, 0);
        acc21 = __builtin_amdgcn_mfma_f32_16x16x32_bf16(a21, b2, acc21, 0, 0, 0);
    }

#pragma unroll
    for (int i = 0; i < 4; i++) {
        int p0l = pbase + g * 4 + i;
        int p1l = pbase + 16 + g * 4 + i;
        float v0 = lrelu(acc20[i]);
        float v1 = lrelu(acc21[i]);
        curb[(size_t)p0l * 16 + r16] = f2bf(v0);   // sequential 32B per quarter-wave
        curb[(size_t)p1l * 16 + r16] = f2bf(v1);
        if (WOUT) {
            int eo0 = perm[p0l];   // broadcast read (same addr across r16 lanes)
            int eo1 = perm[p1l];
            oc[(size_t)eo0 * 16 + r16] = v0;       // 64B contiguous scatter
            oc[(size_t)eo1 * 16 + r16] = v1;
        }
    }
}

// ---- gather-mean variants ----
__global__ void __launch_bounds__(256) gather_mean(const int* __restrict__ off,
                                                   const int* __restrict__ perm,
                                                   const float* __restrict__ ecur,
                                                   float* __restrict__ msg) {
    const int wave = threadIdx.x >> 6;
    const int lane = threadIdx.x & 63;
    const int i = blockIdx.x * 4 + wave;
    const int c = lane & 15;
    const int sub = lane >> 4;
    const int p0 = off[i], p1 = off[i + 1];
    float sum = 0.f;
    for (int p = p0 + sub; p < p1; p += 4)
        sum += ecur[(size_t)perm[p] * 16 + c];
    sum += __shfl_xor(sum, 16, 64);
    sum += __shfl_xor(sum, 32, 64);
    if (lane < 16) {
        float inv = 1.0f / fmaxf((float)(p1 - p0), 1.0f);
        msg[(size_t)i * 16 + c] = sum * inv;
    }
}

__global__ void __launch_bounds__(256) gather_mean_b16(const int* __restrict__ off,
                                                       const int* __restrict__ perm,
                                                       const unsigned short* __restrict__ ecurb,
                                                       float* __restrict__ msg) {
    const int wave = threadIdx.x >> 6;
    const int lane = threadIdx.x & 63;
    const int i = blockIdx.x * 4 + wave;
    const int c = lane & 15;
    const int sub = lane >> 4;
    const int p0 = off[i], p1 = off[i + 1];
    float sum = 0.f;
    for (int p = p0 + sub; p < p1; p += 4)
        sum += bf2f((unsigned int)ecurb[(size_t)perm[p] * 16 + c]);
    sum += __shfl_xor(sum, 16, 64);
    sum += __shfl_xor(sum, 32, 64);
    if (lane < 16) {
        float inv = 1.0f / fmaxf((float)(p1 - p0), 1.0f);
        msg[(size_t)i * 16 + c] = sum * inv;
    }
}

// perm-ordered history: CSR range is contiguous in ecurb -> pure streaming
__global__ void __launch_bounds__(256) gather_mean_seq(const int* __restrict__ off,
                                                       const unsigned short* __restrict__ ecurb,
                                                       float* __restrict__ msg) {
    const int wave = threadIdx.x >> 6;
    const int lane = threadIdx.x & 63;
    const int i = blockIdx.x * 4 + wave;
    const int c = lane & 15;
    const int sub = lane >> 4;
    const int p0 = off[i], p1 = off[i + 1];
    float sum = 0.f;
    for (int p = p0 + sub; p < p1; p += 4)
        sum += bf2f((unsigned int)ecurb[(size_t)p * 16 + c]);
    sum += __shfl_xor(sum, 16, 64);
    sum += __shfl_xor(sum, 32, 64);
    if (lane < 16) {
        float inv = 1.0f / fmaxf((float)(p1 - p0), 1.0f);
        msg[(size_t)i * 16 + c] = sum * inv;
    }
}

// ---- node MLP: nh=[nc(bf16->f32), msg] (80) -> 56 (relu) -> 32 (relu) ----
__global__ void __launch_bounds__(64) node_mlp(const float* __restrict__ msg,
                                               unsigned short* __restrict__ ncb,
                                               const float* __restrict__ wsW) {
    __shared__ float sl[64 * 81];
    const int l = threadIdx.x;
    const int i = blockIdx.x * 64 + l;
    if (i >= N_NODES) return;
    const float* W0 = wsW + O_NODEW0;
    const float* b0 = wsW + O_NODEB0;
    const float* W1 = wsW + O_NODEW1;
    const float* b1 = wsW + O_NODEB1;

    const uint4* ncp = (const uint4*)(ncb + (size_t)i * 64);
#pragma unroll
    for (int q = 0; q < 8; q++) {
        uint4 u = ncp[q];
        int base = l * 81 + 8 * q;
        sl[base + 0] = bf2f(u.x & 0xffffu); sl[base + 1] = bf2f(u.x >> 16);
        sl[base + 2] = bf2f(u.y & 0xffffu); sl[base + 3] = bf2f(u.y >> 16);
        sl[base + 4] = bf2f(u.z & 0xffffu); sl[base + 5] = bf2f(u.z >> 16);
        sl[base + 6] = bf2f(u.w & 0xffffu); sl[base + 7] = bf2f(u.w >> 16);
    }
    const float4* mp = (const float4*)(msg + (size_t)i * 16);
#pragma unroll
    for (int q = 0; q < 4; q++) {
        float4 v = mp[q];
        int base = l * 81 + 64 + 4 * q;
        sl[base] = v.x; sl[base + 1] = v.y; sl[base + 2] = v.z; sl[base + 3] = v.w;
    }

    float h[56];
#pragma unroll
    for (int q = 0; q < 14; q++) {
        float4 b = ((const float4*)b0)[q];
        h[4 * q] = b.x; h[4 * q + 1] = b.y; h[4 * q + 2] = b.z; h[4 * q + 3] = b.w;
    }
    for (int k = 0; k < 80; k++) {
        float v = sl[l * 81 + k];
        const float4* w = (const float4*)(W0 + k * 56);
#pragma unroll
        for (int q = 0; q < 14; q++) {
            float4 wv = w[q];
            h[4 * q]     = fmaf(v, wv.x, h[4 * q]);
            h[4 * q + 1] = fmaf(v, wv.y, h[4 * q + 1]);
            h[4 * q + 2] = fmaf(v, wv.z, h[4 * q + 2]);
            h[4 * q + 3] = fmaf(v, wv.w, h[4 * q + 3]);
        }
    }
#pragma unroll
    for (int j = 0; j < 56; j++) sl[l * 81 + j] = fmaxf(h[j], 0.f);

    float o[32];
#pragma unroll
    for (int q = 0; q < 8; q++) {
        float4 b = ((const float4*)b1)[q];
        o[4 * q] = b.x; o[4 * q + 1] = b.y; o[4 * q + 2] = b.z; o[4 * q + 3] = b.w;
    }
    for (int j = 0; j < 56; j++) {
        float v = sl[l * 81 + j];
        const float4* w = (const float4*)(W1 + j * 32);
#pragma unroll
        for (int q = 0; q < 8; q++) {
            float4 wv = w[q];
            o[4 * q]     = fmaf(v, wv.x, o[4 * q]);
            o[4 * q + 1] = fmaf(v, wv.y, o[4 * q + 1]);
            o[4 * q + 2] = fmaf(v, wv.z, o[4 * q + 2]);
            o[4 * q + 3] = fmaf(v, wv.w, o[4 * q + 3]);
        }
    }
    // write n half back as bf16
    uint4* nout = (uint4*)(ncb + (size_t)i * 64 + 32);
#pragma unroll
    for (int q = 0; q < 4; q++) {
        unsigned int w0 = (unsigned int)f2bf(fmaxf(o[8 * q + 0], 0.f)) |
                          ((unsigned int)f2bf(fmaxf(o[8 * q + 1], 0.f)) << 16);
        unsigned int w1 = (unsigned int)f2bf(fmaxf(o[8 * q + 2], 0.f)) |
                          ((unsigned int)f2bf(fmaxf(o[8 * q + 3], 0.f)) << 16);
        unsigned int w2 = (unsigned int)f2bf(fmaxf(o[8 * q + 4], 0.f)) |
                          ((unsigned int)f2bf(fmaxf(o[8 * q + 5], 0.f)) << 16);
        unsigned int w3 = (unsigned int)f2bf(fmaxf(o[8 * q + 6], 0.f)) |
                          ((unsigned int)f2bf(fmaxf(o[8 * q + 7], 0.f)) << 16);
        nout[q] = make_uint4(w0, w1, w2, w3);
    }
}

extern "C" void kernel_launch(void* const* d_in, const int* in_sizes, int n_in,
                              void* d_out, int out_size, void* d_ws, size_t ws_size,
                              hipStream_t stream) {
    (void)in_sizes; (void)n_in; (void)out_size;
    const float* x  = (const float*)d_in[0];
    const int* eidx = (const int*)d_in[1];
    const float* ea = (const float*)d_in[2];
    float* out = (float*)d_out;   // f32 output: 5 slots x E x 16

    // d_ws layout (byte offsets):
    //   wsW @0 (85232) | flags @85232 (16) | cnti @85248 (200000) | off @285248 (200016)
    //   cursor @485264 (200000) | perm @685264 (6400000) | ncb @7085264 (6400000, u16)
    //   wT @13485264 (28672, u16) | msg @13513936 (3200000, f32)
    //   [big] e0b @16714240 | rb0 | rb1 (each 51,200,000 B, bf16 E x 16)
    //   [perm] rcp @170314240 (12,800,000, int2) | pose @183114240 (6,400,000, int)
    char* wsb = (char*)d_ws;
    float* wsW  = (float*)(wsb + 0);
    int* flags  = (int*)(wsb + 85232);
    int* cnti   = (int*)(wsb + 85248);
    int* off    = (int*)(wsb + 285248);
    int* cursor = (int*)(wsb + 485264);
    int* perm   = (int*)(wsb + 685264);
    unsigned short* ncb = (unsigned short*)(wsb + 7085264);
    unsigned short* wT  = (unsigned short*)(wsb + 13485264);
    float* msg  = (float*)(wsb + 13513936);
    const size_t WS_BASE = 16713936ull;
    unsigned short* e0b = (unsigned short*)(wsb + 16714240);
    unsigned short* rb0 = e0b + (size_t)N_EDGES * 16;
    unsigned short* rb1 = rb0 + (size_t)N_EDGES * 16;
    const size_t WS_BIG = 16714240ull + 3ull * 51200000ull;   // ~170.3 MB
    int2* rcp = (int2*)(wsb + 170314240ull);
    int* pose = (int*)(wsb + 183114240ull);
    const size_t WS_PERM = 189514240ull;                      // ~189.5 MB
    if (ws_size < WS_BASE) return;  // refuse to corrupt memory
    const bool big  = (ws_size >= WS_BIG);
    const bool prm  = (ws_size >= WS_PERM);

    WPack P;
    static const int offs[15] = {0, 108, 126, 450, 468, 756, 772, 13572, 13652,
                                 14932, 14948, 19428, 19484, 21276, 21308};
    for (int a = 0; a < 14; a++) P.p[a] = (const float*)d_in[3 + a];
    for (int a = 0; a < 15; a++) P.off[a] = offs[a];

    detect_flags<<<1, 64, 0, stream>>>(eidx, flags);
    copy_w<<<14, 256, 0, stream>>>(P, wsW);
    build_wT<<<56, 256, 0, stream>>>((const float*)d_in[9], (const float*)d_in[11], wT);
    init_nodes<<<196, 256, 0, stream>>>(x, ncb, cnti);
    count_edges<<<N_EDGES / 256, 256, 0, stream>>>(eidx, flags, cnti);
    scan_offsets<<<1, 256, 0, stream>>>(cnti, off, cursor);
    if (prm)
        build_perm<1><<<N_EDGES / 256, 256, 0, stream>>>(eidx, flags, cursor, perm, rcp, pose);
    else
        build_perm<0><<<N_EDGES / 256, 256, 0, stream>>>(eidx, flags, cursor, perm, nullptr, nullptr);

    if (prm) {
        // perm-ordered bf16 history: sequential history, clustered row gathers
        encoder<2><<<N_EDGES / 256, 256, 0, stream>>>(ea, wsW, out, e0b, pose);
        unsigned short* rings[2] = {rb0, rb1};
        for (int t = 1; t <= 6; t++) {
            unsigned short* prevb = (t == 1) ? e0b : rings[(t - 1) & 1];
            unsigned short* curb  = rings[t & 1];
            if (t == 1)
                edge_mfma_perm<0><<<N_EDGES / 128, 256, 0, stream>>>(
                    ncb, e0b, prevb, curb, rcp, perm, wsW, wT, out);
            else
                edge_mfma_perm<1><<<N_EDGES / 128, 256, 0, stream>>>(
                    ncb, e0b, prevb, curb, rcp, perm, wsW, wT,
                    out + (size_t)(t - 2) * N_EDGES * 16);
            if (t < 6) {
                gather_mean_seq<<<12500, 256, 0, stream>>>(off, curb, msg);
                node_mlp<<<782, 64, 0, stream>>>(msg, ncb, wsW);
            }
        }
    } else if (big) {
        // bf16 e-history ring in ws, edge-id order (round-14 path)
        encoder<1><<<N_EDGES / 256, 256, 0, stream>>>(ea, wsW, out, e0b, nullptr);
        unsigned short* rings[2] = {rb0, rb1};
        for (int t = 1; t <= 6; t++) {
            unsigned short* prevb = (t == 1) ? e0b : rings[(t - 1) & 1];
            unsigned short* curb  = rings[t & 1];
            if (t == 1)
                edge_mfma_b16<0><<<N_EDGES / 128, 256, 0, stream>>>(
                    ncb, e0b, prevb, curb, eidx, flags, wsW, wT, out);
            else
                edge_mfma_b16<1><<<N_EDGES / 128, 256, 0, stream>>>(
                    ncb, e0b, prevb, curb, eidx, flags, wsW, wT,
                    out + (size_t)(t - 2) * N_EDGES * 16);
            if (t < 6) {
                gather_mean_b16<<<12500, 256, 0, stream>>>(off, perm, curb, msg);
                node_mlp<<<782, 64, 0, stream>>>(msg, ncb, wsW);
            }
        }
    } else {
        // f32 history in d_out slot ring (round-12 path)
        encoder<0><<<N_EDGES / 256, 256, 0, stream>>>(ea, wsW, out, nullptr, nullptr);
        const int prevs[6] = {4, 0, 0, 1, 2, 3};
        const int curs[6]  = {0, 0, 1, 2, 3, 4};
        for (int t = 1; t <= 6; t++) {
            edge_mfma<<<N_EDGES / 128, 256, 0, stream>>>(ncb, out, 4, prevs[t - 1],
                                                         curs[t - 1], eidx, flags, wsW,
                                                         wT, out);
            if (t < 6) {
                gather_mean<<<12500, 256, 0, stream>>>(
                    off, perm, out + (size_t)curs[t - 1] * N_EDGES * 16, msg);
                node_mlp<<<782, 64, 0, stream>>>(msg, ncb, wsW);
            }
        }
    }
}

// Round 16
// 1567.119 us; speedup vs baseline: 1.2282x; 1.0236x over previous
//
#include <hip/hip_runtime.h>

#define N_NODES 50000
#define N_EDGES 1600000

// weight offsets (floats) inside the weights region of d_ws
#define O_ENCW0 0
#define O_ENCB0 108
#define O_ENCW1 126
#define O_ENCB1 450
#define O_ENCW2 468
#define O_ENCB2 756
#define O_EDGEW0 772
#define O_EDGEB0 13572
#define O_EDGEW1 13652
#define O_EDGEB1 14932
#define O_NODEW0 14948
#define O_NODEB0 19428
#define O_NODEW1 19484
#define O_NODEB1 21276
#define W_TOTAL 21308

typedef __attribute__((ext_vector_type(8))) short bf16x8;
typedef __attribute__((ext_vector_type(4))) short bf16x4;
typedef __attribute__((ext_vector_type(4))) float f32x4;

__device__ __forceinline__ float bf2f(unsigned int u) {
    return __uint_as_float(u << 16);
}
__device__ __forceinline__ unsigned short f2bf(float f) {
    unsigned int u = __float_as_uint(f);
    u += 0x7fffu + ((u >> 16) & 1u);   // RNE (finite values only here)
    return (unsigned short)(u >> 16);
}
__device__ __forceinline__ float lrelu(float x) { return x > 0.f ? x : 0.01f * x; }

__device__ __forceinline__ bf16x8 pack8(float4 a, float4 b) {
    bf16x8 r;
    r[0] = (short)f2bf(a.x); r[1] = (short)f2bf(a.y);
    r[2] = (short)f2bf(a.z); r[3] = (short)f2bf(a.w);
    r[4] = (short)f2bf(b.x); r[5] = (short)f2bf(b.y);
    r[6] = (short)f2bf(b.z); r[7] = (short)f2bf(b.w);
    return r;
}

struct WPack {
    const float* p[14];
    int off[15];
};

// ---- detect flag: edge_index is int64 (high words of first 64 entries all zero) ----
__global__ void detect_flags(const int* __restrict__ eidx, int* __restrict__ flags) {
    int t = threadIdx.x;  // 64 threads
    int v = eidx[2 * t + 1];
    unsigned long long bi = __ballot(v != 0);
    if (t == 0) flags[0] = (bi == 0ull) ? 1 : 0;
}

__device__ __forceinline__ void load_rc(const int* eidx, int flag64, int e, int& r, int& c) {
    if (flag64) {
        const long long* e64 = (const long long*)eidx;
        r = (int)e64[e];
        c = (int)e64[N_EDGES + e];
    } else {
        r = eidx[e];
        c = eidx[N_EDGES + e];
    }
}
__device__ __forceinline__ int load_r(const int* eidx, int flag64, int e) {
    return flag64 ? (int)((const long long*)eidx)[e] : eidx[e];
}

// ---- copy all f32 weight/bias arrays into contiguous ws region ----
__global__ void copy_w(WPack P, float* __restrict__ dst) {
    int a = blockIdx.x;
    const float* s = P.p[a];
    int n = P.off[a + 1] - P.off[a];
    float* d = dst + P.off[a];
    for (int i = threadIdx.x; i < n; i += 256) d[i] = s[i];
}

// ---- build transposed bf16 weights for MFMA B-fragments (edge MLP) ----
__global__ void build_wT(const float* __restrict__ w0,
                         const float* __restrict__ w1,
                         unsigned short* __restrict__ wT) {
    int t = blockIdx.x * 256 + threadIdx.x;  // 56 * 256 = 14336
    if (t < 12800) {
        int col = t / 160, k = t % 160;
        wT[t] = f2bf(w0[k * 80 + col]);
    } else if (t < 14336) {
        int u = t - 12800;
        int col = u / 96, k = u % 96;
        wT[t] = (k < 80) ? f2bf(w1[k * 16 + col]) : (unsigned short)0;
    }
}

// ---- build transposed bf16 node-MLP weights ----
// wn[0..6143]    = nodeW0T [64 cols][96 k]  (cols 56..63 and k 80..95 zero)
// wn[6144..8191] = nodeW1T [32 cols][64 k]  (k 56..63 zero)
__global__ void build_wnT(const float* __restrict__ nw0, const float* __restrict__ nw1,
                          unsigned short* __restrict__ wn) {
    int t = blockIdx.x * 256 + threadIdx.x;   // 32*256 = 8192
    if (t < 6144) {
        int col = t / 96, k = t % 96;
        wn[t] = (col < 56 && k < 80) ? f2bf(nw0[k * 56 + col]) : (unsigned short)0;
    } else if (t < 8192) {
        int u = t - 6144;
        int col = u / 64, k = u % 64;
        wn[t] = (k < 56) ? f2bf(nw1[k * 32 + col]) : (unsigned short)0;
    }
}

// ---- n0 = lrelu(x) (f32 in) stored bf16; ncb = [n0, n0]; zero cnti ----
__global__ void __launch_bounds__(256) init_nodes(const float* __restrict__ x,
                                                  unsigned short* __restrict__ ncb,
                                                  int* __restrict__ cnti) {
    int i = blockIdx.x * 256 + threadIdx.x;
    if (i >= N_NODES) return;
    const float4* xin = (const float4*)(x + (size_t)i * 32);  // 8 float4
    uint4* np = (uint4*)(ncb + (size_t)i * 64);
#pragma unroll
    for (int q = 0; q < 4; q++) {
        float4 a = xin[2 * q];
        float4 b = xin[2 * q + 1];
        unsigned int w0 = (unsigned int)f2bf(lrelu(a.x)) | ((unsigned int)f2bf(lrelu(a.y)) << 16);
        unsigned int w1 = (unsigned int)f2bf(lrelu(a.z)) | ((unsigned int)f2bf(lrelu(a.w)) << 16);
        unsigned int w2 = (unsigned int)f2bf(lrelu(b.x)) | ((unsigned int)f2bf(lrelu(b.y)) << 16);
        unsigned int w3 = (unsigned int)f2bf(lrelu(b.z)) | ((unsigned int)f2bf(lrelu(b.w)) << 16);
        uint4 o = make_uint4(w0, w1, w2, w3);
        np[q] = o;       // n0 half (bf16)
        np[4 + q] = o;   // n half (n == n0 initially)
    }
    cnti[i] = 0;
}

// ---- CSR build: count, scan, bucket ----
__global__ void count_edges(const int* __restrict__ eidx, const int* __restrict__ flags,
                            int* __restrict__ cnti) {
    int e = blockIdx.x * 256 + threadIdx.x;
    atomicAdd(&cnti[load_r(eidx, flags[0], e)], 1);
}

__global__ void __launch_bounds__(256) scan_offsets(const int* __restrict__ cnti,
                                                    int* __restrict__ off,
                                                    int* __restrict__ cursor) {
    __shared__ int ls[256];
    const int t = threadIdx.x;
    const int lo = t * 196;
    const int hi = min(lo + 196, N_NODES);
    int sum = 0;
    for (int i = lo; i < hi; i++) sum += cnti[i];
    ls[t] = sum;
    __syncthreads();
    for (int d = 1; d < 256; d <<= 1) {
        int v = (t >= d) ? ls[t - d] : 0;
        __syncthreads();
        ls[t] += v;
        __syncthreads();
    }
    int run = (t == 0) ? 0 : ls[t - 1];
    for (int i = lo; i < hi; i++) {
        off[i] = run;
        cursor[i] = run;
        run += cnti[i];
    }
    if (t == 255) off[N_NODES] = run;   // == N_EDGES
}

// EXT=1 additionally records rcp[pos]=(row,col) and pose[e]=pos for the perm path
template <int EXT>
__global__ void build_perm(const int* __restrict__ eidx, const int* __restrict__ flags,
                           int* __restrict__ cursor, int* __restrict__ perm,
                           int2* __restrict__ rcp, int* __restrict__ pose) {
    int e = blockIdx.x * 256 + threadIdx.x;
    int r, c;
    load_rc(eidx, flags[0], e, r, c);
    int pos = atomicAdd(&cursor[r], 1);
    perm[pos] = e;
    if (EXT) {
        rcp[pos] = make_int2(r, c);
        pose[e] = pos;
    }
}

// ---- encoder MLP 6->18->18->16 (lrelu each) ----
// MODE 0: e0 f32 -> slot4 of out; MODE 1: e0 bf16 -> e0b[e]; MODE 2: bf16 -> e0b[pose[e]]
template <int MODE>
__global__ void __launch_bounds__(256) encoder(const float* __restrict__ ea,
                                               const float* __restrict__ wsW,
                                               float* __restrict__ outbase,
                                               unsigned short* __restrict__ e0b,
                                               const int* __restrict__ pose) {
    int e = blockIdx.x * 256 + threadIdx.x;  // E % 256 == 0
    const float* ap = ea + (size_t)e * 6;
    float a[6];
#pragma unroll
    for (int k = 0; k < 6; k++) a[k] = ap[k];

    float h1[18];
#pragma unroll
    for (int j = 0; j < 18; j++) h1[j] = wsW[O_ENCB0 + j];
#pragma unroll
    for (int k = 0; k < 6; k++) {
        float v = a[k];
#pragma unroll
        for (int j = 0; j < 18; j++) h1[j] = fmaf(v, wsW[O_ENCW0 + k * 18 + j], h1[j]);
    }
#pragma unroll
    for (int j = 0; j < 18; j++) h1[j] = lrelu(h1[j]);

    float h2[18];
#pragma unroll
    for (int j = 0; j < 18; j++) h2[j] = wsW[O_ENCB1 + j];
#pragma unroll
    for (int k = 0; k < 18; k++) {
        float v = h1[k];
#pragma unroll
        for (int j = 0; j < 18; j++) h2[j] = fmaf(v, wsW[O_ENCW1 + k * 18 + j], h2[j]);
    }
#pragma unroll
    for (int j = 0; j < 18; j++) h2[j] = lrelu(h2[j]);

    float o[16];
#pragma unroll
    for (int j = 0; j < 16; j++) o[j] = wsW[O_ENCB2 + j];
#pragma unroll
    for (int k = 0; k < 18; k++) {
        float v = h2[k];
#pragma unroll
        for (int j = 0; j < 16; j++) o[j] = fmaf(v, wsW[O_ENCW2 + k * 16 + j], o[j]);
    }
    if (MODE == 0) {
        float4* ow = (float4*)(outbase + (size_t)4 * N_EDGES * 16 + (size_t)e * 16);
#pragma unroll
        for (int q = 0; q < 4; q++)
            ow[q] = make_float4(lrelu(o[4 * q]), lrelu(o[4 * q + 1]),
                                lrelu(o[4 * q + 2]), lrelu(o[4 * q + 3]));
    } else {
        unsigned int pw[8];
#pragma unroll
        for (int q = 0; q < 8; q++) {
            float a0 = lrelu(o[2 * q]), a1 = lrelu(o[2 * q + 1]);
            pw[q] = (unsigned int)f2bf(a0) | ((unsigned int)f2bf(a1) << 16);
        }
        size_t pos = (MODE == 2) ? (size_t)pose[e] : (size_t)e;
        uint4* ow = (uint4*)(e0b + pos * 16);
        ow[0] = make_uint4(pw[0], pw[1], pw[2], pw[3]);
        ow[1] = make_uint4(pw[4], pw[5], pw[6], pw[7]);
    }
}

// ---- edge update core (dual 16-edge groups, both layers MFMA) ----
// MFMA 16x16x32 frags (m97/m89-verified): A row=lane&15, k=st*32+(lane>>4)*8+j;
// B col=lane&15, same k; D col=lane&15, row=4*(lane>>4)+reg.
// act1 per-wave bf16 [32][104]; lgkmcnt+sched_barrier fences (rule #18), no barrier.

// (A) f32-history fallback (round-12 proven)
__global__ void __launch_bounds__(256) edge_mfma(const unsigned short* __restrict__ ncb,
                                                 const float* __restrict__ outb_c,
                                                 int slot_e0, int slot_prev, int slot_cur,
                                                 const int* __restrict__ eidx,
                                                 const int* __restrict__ flags,
                                                 const float* __restrict__ wsW,
                                                 const unsigned short* __restrict__ wT,
                                                 float* __restrict__ outb) {
    __shared__ unsigned short act1[4][32 * 104];
    const int lane = threadIdx.x & 63;
    const int wave = threadIdx.x >> 6;
    const int r16 = lane & 15;
    const int g = lane >> 4;
    const int flag64 = flags[0];
    unsigned short* aw = act1[wave];

    const int ebase = blockIdx.x * 128 + wave * 32;
    const float* e0s = outb_c + (size_t)slot_e0 * N_EDGES * 16;
    const float* eps = outb_c + (size_t)slot_prev * N_EDGES * 16;

#pragma unroll
    for (int u = 0; u < 2; u++) {
        bf16x4 z4 = {0, 0, 0, 0};
        *(bf16x4*)&aw[(u * 16 + r16) * 104 + 80 + g * 4] = z4;
    }

    bf16x8 a[2][5];
#pragma unroll
    for (int u = 0; u < 2; u++) {
        const int el = ebase + u * 16 + r16;
        int r_el, c_el;
        load_rc(eidx, flag64, el, r_el, c_el);
        a[u][0] = *(const bf16x8*)(ncb + (size_t)r_el * 64 + g * 8);
        a[u][1] = *(const bf16x8*)(ncb + (size_t)r_el * 64 + 32 + g * 8);
        a[u][2] = *(const bf16x8*)(ncb + (size_t)c_el * 64 + g * 8);
        a[u][3] = *(const bf16x8*)(ncb + (size_t)c_el * 64 + 32 + g * 8);
        const float* src = (g < 2) ? e0s : eps;
        const float4* p = (const float4*)(src + (size_t)el * 16 + (g & 1) * 8);
        a[u][4] = pack8(p[0], p[1]);
    }

#pragma unroll
    for (int t = 0; t < 5; t++) {
        float bv = wsW[O_EDGEB0 + t * 16 + r16];
        f32x4 acc0 = {bv, bv, bv, bv};
        f32x4 acc1 = {bv, bv, bv, bv};
#pragma unroll
        for (int st = 0; st < 5; st++) {
            bf16x8 b = *(const bf16x8*)(wT + (t * 16 + r16) * 160 + st * 32 + g * 8);
            acc0 = __builtin_amdgcn_mfma_f32_16x16x32_bf16(a[0][st], b, acc0, 0, 0, 0);
            acc1 = __builtin_amdgcn_mfma_f32_16x16x32_bf16(a[1][st], b, acc1, 0, 0, 0);
        }
#pragma unroll
        for (int i = 0; i < 4; i++) {
            aw[(g * 4 + i) * 104 + t * 16 + r16]      = f2bf(lrelu(acc0[i]));
            aw[(16 + g * 4 + i) * 104 + t * 16 + r16] = f2bf(lrelu(acc1[i]));
        }
    }
    asm volatile("s_waitcnt lgkmcnt(0)" ::: "memory");
    __builtin_amdgcn_sched_barrier(0);

    float bv2 = wsW[O_EDGEB1 + r16];
    f32x4 acc20 = {bv2, bv2, bv2, bv2};
    f32x4 acc21 = {bv2, bv2, bv2, bv2};
#pragma unroll
    for (int st = 0; st < 3; st++) {
        bf16x8 b2 = *(const bf16x8*)(wT + 12800 + r16 * 96 + st * 32 + g * 8);
        bf16x8 a20 = *(const bf16x8*)&aw[r16 * 104 + st * 32 + g * 8];
        bf16x8 a21 = *(const bf16x8*)&aw[(16 + r16) * 104 + st * 32 + g * 8];
        acc20 = __builtin_amdgcn_mfma_f32_16x16x32_bf16(a20, b2, acc20, 0, 0, 0);
        acc21 = __builtin_amdgcn_mfma_f32_16x16x32_bf16(a21, b2, acc21, 0, 0, 0);
    }

    float* oc = outb + (size_t)slot_cur * N_EDGES * 16;
#pragma unroll
    for (int i = 0; i < 4; i++) {
        int eg0 = ebase + g * 4 + i;
        int eg1 = ebase + 16 + g * 4 + i;
        oc[(size_t)eg0 * 16 + r16] = lrelu(acc20[i]);
        oc[(size_t)eg1 * 16 + r16] = lrelu(acc21[i]);
    }
}

// (B) bf16-history, edge-id order (round-14 proven)
template <int WOUT>
__global__ void __launch_bounds__(256) edge_mfma_b16(const unsigned short* __restrict__ ncb,
                                                     const unsigned short* __restrict__ e0b,
                                                     const unsigned short* __restrict__ prevb,
                                                     unsigned short* __restrict__ curb,
                                                     const int* __restrict__ eidx,
                                                     const int* __restrict__ flags,
                                                     const float* __restrict__ wsW,
                                                     const unsigned short* __restrict__ wT,
                                                     float* __restrict__ oc) {
    __shared__ unsigned short act1[4][32 * 104];
    const int lane = threadIdx.x & 63;
    const int wave = threadIdx.x >> 6;
    const int r16 = lane & 15;
    const int g = lane >> 4;
    const int flag64 = flags[0];
    unsigned short* aw = act1[wave];

    const int ebase = blockIdx.x * 128 + wave * 32;

#pragma unroll
    for (int u = 0; u < 2; u++) {
        bf16x4 z4 = {0, 0, 0, 0};
        *(bf16x4*)&aw[(u * 16 + r16) * 104 + 80 + g * 4] = z4;
    }

    bf16x8 a[2][5];
#pragma unroll
    for (int u = 0; u < 2; u++) {
        const int el = ebase + u * 16 + r16;
        int r_el, c_el;
        load_rc(eidx, flag64, el, r_el, c_el);
        a[u][0] = *(const bf16x8*)(ncb + (size_t)r_el * 64 + g * 8);
        a[u][1] = *(const bf16x8*)(ncb + (size_t)r_el * 64 + 32 + g * 8);
        a[u][2] = *(const bf16x8*)(ncb + (size_t)c_el * 64 + g * 8);
        a[u][3] = *(const bf16x8*)(ncb + (size_t)c_el * 64 + 32 + g * 8);
        const unsigned short* src = (g < 2) ? e0b : prevb;
        a[u][4] = *(const bf16x8*)(src + (size_t)el * 16 + (g & 1) * 8);
    }

#pragma unroll
    for (int t = 0; t < 5; t++) {
        float bv = wsW[O_EDGEB0 + t * 16 + r16];
        f32x4 acc0 = {bv, bv, bv, bv};
        f32x4 acc1 = {bv, bv, bv, bv};
#pragma unroll
        for (int st = 0; st < 5; st++) {
            bf16x8 b = *(const bf16x8*)(wT + (t * 16 + r16) * 160 + st * 32 + g * 8);
            acc0 = __builtin_amdgcn_mfma_f32_16x16x32_bf16(a[0][st], b, acc0, 0, 0, 0);
            acc1 = __builtin_amdgcn_mfma_f32_16x16x32_bf16(a[1][st], b, acc1, 0, 0, 0);
        }
#pragma unroll
        for (int i = 0; i < 4; i++) {
            aw[(g * 4 + i) * 104 + t * 16 + r16]      = f2bf(lrelu(acc0[i]));
            aw[(16 + g * 4 + i) * 104 + t * 16 + r16] = f2bf(lrelu(acc1[i]));
        }
    }
    asm volatile("s_waitcnt lgkmcnt(0)" ::: "memory");
    __builtin_amdgcn_sched_barrier(0);

    float bv2 = wsW[O_EDGEB1 + r16];
    f32x4 acc20 = {bv2, bv2, bv2, bv2};
    f32x4 acc21 = {bv2, bv2, bv2, bv2};
#pragma unroll
    for (int st = 0; st < 3; st++) {
        bf16x8 b2 = *(const bf16x8*)(wT + 12800 + r16 * 96 + st * 32 + g * 8);
        bf16x8 a20 = *(const bf16x8*)&aw[r16 * 104 + st * 32 + g * 8];
        bf16x8 a21 = *(const bf16x8*)&aw[(16 + r16) * 104 + st * 32 + g * 8];
        acc20 = __builtin_amdgcn_mfma_f32_16x16x32_bf16(a20, b2, acc20, 0, 0, 0);
        acc21 = __builtin_amdgcn_mfma_f32_16x16x32_bf16(a21, b2, acc21, 0, 0, 0);
    }

#pragma unroll
    for (int i = 0; i < 4; i++) {
        int eg0 = ebase + g * 4 + i;
        int eg1 = ebase + 16 + g * 4 + i;
        float v0 = lrelu(acc20[i]);
        float v1 = lrelu(acc21[i]);
        curb[(size_t)eg0 * 16 + r16] = f2bf(v0);
        curb[(size_t)eg1 * 16 + r16] = f2bf(v1);
        if (WOUT) {
            oc[(size_t)eg0 * 16 + r16] = v0;
            oc[(size_t)eg1 * 16 + r16] = v1;
        }
    }
}

// (C) bf16-history, PERM (CSR) order (round-15 proven)
template <int WOUT>
__global__ void __launch_bounds__(256) edge_mfma_perm(const unsigned short* __restrict__ ncb,
                                                      const unsigned short* __restrict__ e0b,
                                                      const unsigned short* __restrict__ prevb,
                                                      unsigned short* __restrict__ curb,
                                                      const int2* __restrict__ rcp,
                                                      const int* __restrict__ perm,
                                                      const float* __restrict__ wsW,
                                                      const unsigned short* __restrict__ wT,
                                                      float* __restrict__ oc) {
    __shared__ unsigned short act1[4][32 * 104];
    const int lane = threadIdx.x & 63;
    const int wave = threadIdx.x >> 6;
    const int r16 = lane & 15;
    const int g = lane >> 4;
    unsigned short* aw = act1[wave];

    const int pbase = blockIdx.x * 128 + wave * 32;

#pragma unroll
    for (int u = 0; u < 2; u++) {
        bf16x4 z4 = {0, 0, 0, 0};
        *(bf16x4*)&aw[(u * 16 + r16) * 104 + 80 + g * 4] = z4;
    }

    bf16x8 a[2][5];
#pragma unroll
    for (int u = 0; u < 2; u++) {
        const int pl = pbase + u * 16 + r16;
        int2 rc = rcp[pl];                      // sequential 8B
        a[u][0] = *(const bf16x8*)(ncb + (size_t)rc.x * 64 + g * 8);
        a[u][1] = *(const bf16x8*)(ncb + (size_t)rc.x * 64 + 32 + g * 8);
        a[u][2] = *(const bf16x8*)(ncb + (size_t)rc.y * 64 + g * 8);
        a[u][3] = *(const bf16x8*)(ncb + (size_t)rc.y * 64 + 32 + g * 8);
        const unsigned short* src = (g < 2) ? e0b : prevb;
        a[u][4] = *(const bf16x8*)(src + (size_t)pl * 16 + (g & 1) * 8);  // sequential
    }

#pragma unroll
    for (int t = 0; t < 5; t++) {
        float bv = wsW[O_EDGEB0 + t * 16 + r16];
        f32x4 acc0 = {bv, bv, bv, bv};
        f32x4 acc1 = {bv, bv, bv, bv};
#pragma unroll
        for (int st = 0; st < 5; st++) {
            bf16x8 b = *(const bf16x8*)(wT + (t * 16 + r16) * 160 + st * 32 + g * 8);
            acc0 = __builtin_amdgcn_mfma_f32_16x16x32_bf16(a[0][st], b, acc0, 0, 0, 0);
            acc1 = __builtin_amdgcn_mfma_f32_16x16x32_bf16(a[1][st], b, acc1, 0, 0, 0);
        }
#pragma unroll
        for (int i = 0; i < 4; i++) {
            aw[(g * 4 + i) * 104 + t * 16 + r16]      = f2bf(lrelu(acc0[i]));
            aw[(16 + g * 4 + i) * 104 + t * 16 + r16] = f2bf(lrelu(acc1[i]));
        }
    }
    asm volatile("s_waitcnt lgkmcnt(0)" ::: "memory");
    __builtin_amdgcn_sched_barrier(0);

    float bv2 = wsW[O_EDGEB1 + r16];
    f32x4 acc20 = {bv2, bv2, bv2, bv2};
    f32x4 acc21 = {bv2, bv2, bv2, bv2};
#pragma unroll
    for (int st = 0; st < 3; st++) {
        bf16x8 b2 = *(const bf16x8*)(wT + 12800 + r16 * 96 + st * 32 + g * 8);
        bf16x8 a20 = *(const bf16x8*)&aw[r16 * 104 + st * 32 + g * 8];
        bf16x8 a21 = *(const bf16x8*)&aw[(16 + r16) * 104 + st * 32 + g * 8];
        acc20 = __builtin_amdgcn_mfma_f32_16x16x32_bf16(a20, b2, acc20, 0, 0, 0);
        acc21 = __builtin_amdgcn_mfma_f32_16x16x32_bf16(a21, b2, acc21, 0, 0, 0);
    }

#pragma unroll
    for (int i = 0; i < 4; i++) {
        int p0l = pbase + g * 4 + i;
        int p1l = pbase + 16 + g * 4 + i;
        float v0 = lrelu(acc20[i]);
        float v1 = lrelu(acc21[i]);
        curb[(size_t)p0l * 16 + r16] = f2bf(v0);
        curb[(size_t)p1l * 16 + r16] = f2bf(v1);
        if (WOUT) {
            int eo0 = perm[p0l];
            int eo1 = perm[p1l];
            oc[(size_t)eo0 * 16 + r16] = v0;
            oc[(size_t)eo1 * 16 + r16] = v1;
        }
    }
}

// ---- gather-mean variants (fallback paths) ----
__global__ void __launch_bounds__(256) gather_mean(const int* __restrict__ off,
                                                   const int* __restrict__ perm,
                                                   const float* __restrict__ ecur,
                                                   float* __restrict__ msg) {
    const int wave = threadIdx.x >> 6;
    const int lane = threadIdx.x & 63;
    const int i = blockIdx.x * 4 + wave;
    const int c = lane & 15;
    const int sub = lane >> 4;
    const int p0 = off[i], p1 = off[i + 1];
    float sum = 0.f;
    for (int p = p0 + sub; p < p1; p += 4)
        sum += ecur[(size_t)perm[p] * 16 + c];
    sum += __shfl_xor(sum, 16, 64);
    sum += __shfl_xor(sum, 32, 64);
    if (lane < 16) {
        float inv = 1.0f / fmaxf((float)(p1 - p0), 1.0f);
        msg[(size_t)i * 16 + c] = sum * inv;
    }
}

__global__ void __launch_bounds__(256) gather_mean_b16(const int* __restrict__ off,
                                                       const int* __restrict__ perm,
                                                       const unsigned short* __restrict__ ecurb,
                                                       float* __restrict__ msg) {
    const int wave = threadIdx.x >> 6;
    const int lane = threadIdx.x & 63;
    const int i = blockIdx.x * 4 + wave;
    const int c = lane & 15;
    const int sub = lane >> 4;
    const int p0 = off[i], p1 = off[i + 1];
    float sum = 0.f;
    for (int p = p0 + sub; p < p1; p += 4)
        sum += bf2f((unsigned int)ecurb[(size_t)perm[p] * 16 + c]);
    sum += __shfl_xor(sum, 16, 64);
    sum += __shfl_xor(sum, 32, 64);
    if (lane < 16) {
        float inv = 1.0f / fmaxf((float)(p1 - p0), 1.0f);
        msg[(size_t)i * 16 + c] = sum * inv;
    }
}

// ---- node MLP (fallback paths): nh=[nc, msg] 80 -> 56 (relu) -> 32 (relu) ----
__global__ void __launch_bounds__(64) node_mlp(const float* __restrict__ msg,
                                               unsigned short* __restrict__ ncb,
                                               const float* __restrict__ wsW) {
    __shared__ float sl[64 * 81];
    const int l = threadIdx.x;
    const int i = blockIdx.x * 64 + l;
    if (i >= N_NODES) return;
    const float* W0 = wsW + O_NODEW0;
    const float* b0 = wsW + O_NODEB0;
    const float* W1 = wsW + O_NODEW1;
    const float* b1 = wsW + O_NODEB1;

    const uint4* ncp = (const uint4*)(ncb + (size_t)i * 64);
#pragma unroll
    for (int q = 0; q < 8; q++) {
        uint4 u = ncp[q];
        int base = l * 81 + 8 * q;
        sl[base + 0] = bf2f(u.x & 0xffffu); sl[base + 1] = bf2f(u.x >> 16);
        sl[base + 2] = bf2f(u.y & 0xffffu); sl[base + 3] = bf2f(u.y >> 16);
        sl[base + 4] = bf2f(u.z & 0xffffu); sl[base + 5] = bf2f(u.z >> 16);
        sl[base + 6] = bf2f(u.w & 0xffffu); sl[base + 7] = bf2f(u.w >> 16);
    }
    const float4* mp = (const float4*)(msg + (size_t)i * 16);
#pragma unroll
    for (int q = 0; q < 4; q++) {
        float4 v = mp[q];
        int base = l * 81 + 64 + 4 * q;
        sl[base] = v.x; sl[base + 1] = v.y; sl[base + 2] = v.z; sl[base + 3] = v.w;
    }

    float h[56];
#pragma unroll
    for (int q = 0; q < 14; q++) {
        float4 b = ((const float4*)b0)[q];
        h[4 * q] = b.x; h[4 * q + 1] = b.y; h[4 * q + 2] = b.z; h[4 * q + 3] = b.w;
    }
    for (int k = 0; k < 80; k++) {
        float v = sl[l * 81 + k];
        const float4* w = (const float4*)(W0 + k * 56);
#pragma unroll
        for (int q = 0; q < 14; q++) {
            float4 wv = w[q];
            h[4 * q]     = fmaf(v, wv.x, h[4 * q]);
            h[4 * q + 1] = fmaf(v, wv.y, h[4 * q + 1]);
            h[4 * q + 2] = fmaf(v, wv.z, h[4 * q + 2]);
            h[4 * q + 3] = fmaf(v, wv.w, h[4 * q + 3]);
        }
    }
#pragma unroll
    for (int j = 0; j < 56; j++) sl[l * 81 + j] = fmaxf(h[j], 0.f);

    float o[32];
#pragma unroll
    for (int q = 0; q < 8; q++) {
        float4 b = ((const float4*)b1)[q];
        o[4 * q] = b.x; o[4 * q + 1] = b.y; o[4 * q + 2] = b.z; o[4 * q + 3] = b.w;
    }
    for (int j = 0; j < 56; j++) {
        float v = sl[l * 81 + j];
        const float4* w = (const float4*)(W1 + j * 32);
#pragma unroll
        for (int q = 0; q < 8; q++) {
            float4 wv = w[q];
            o[4 * q]     = fmaf(v, wv.x, o[4 * q]);
            o[4 * q + 1] = fmaf(v, wv.y, o[4 * q + 1]);
            o[4 * q + 2] = fmaf(v, wv.z, o[4 * q + 2]);
            o[4 * q + 3] = fmaf(v, wv.w, o[4 * q + 3]);
        }
    }
    uint4* nout = (uint4*)(ncb + (size_t)i * 64 + 32);
#pragma unroll
    for (int q = 0; q < 4; q++) {
        unsigned int w0 = (unsigned int)f2bf(fmaxf(o[8 * q + 0], 0.f)) |
                          ((unsigned int)f2bf(fmaxf(o[8 * q + 1], 0.f)) << 16);
        unsigned int w1 = (unsigned int)f2bf(fmaxf(o[8 * q + 2], 0.f)) |
                          ((unsigned int)f2bf(fmaxf(o[8 * q + 3], 0.f)) << 16);
        unsigned int w2 = (unsigned int)f2bf(fmaxf(o[8 * q + 4], 0.f)) |
                          ((unsigned int)f2bf(fmaxf(o[8 * q + 5], 0.f)) << 16);
        unsigned int w3 = (unsigned int)f2bf(fmaxf(o[8 * q + 6], 0.f)) |
                          ((unsigned int)f2bf(fmaxf(o[8 * q + 7], 0.f)) << 16);
        nout[q] = make_uint4(w0, w1, w2, w3);
    }
}

// ---- fused gather + node MLP (perm path): 4 waves x 16 nodes; MFMA MLP ----
// Wave-private LDS; gather math bit-identical to gather_mean_seq (sub/c split + shfl).
// Layer1: nh=[nc(64) | msg(16) | 0(16)] K=96, cols pad 56->64 (zero weights kill pads).
// Layer2: K=64 (k 56..63 zero weights). Same MFMA frag conventions as edge kernels.
__global__ void __launch_bounds__(256) node_fused(const int* __restrict__ off,
                                                  const unsigned short* __restrict__ ecurb,
                                                  unsigned short* __restrict__ ncb,
                                                  const float* __restrict__ wsW,
                                                  const unsigned short* __restrict__ wn) {
    __shared__ unsigned short nhs[4][16 * 104];
    __shared__ unsigned short act2[4][16 * 72];
    const int lane = threadIdx.x & 63;
    const int wave = threadIdx.x >> 6;
    const int r16 = lane & 15;
    const int g = lane >> 4;
    unsigned short* nh = nhs[wave];
    unsigned short* a2w = act2[wave];
    const int n0 = blockIdx.x * 64 + wave * 16;

    // stage nc (k 0..63) + zero pad (k 80..95): lane -> node i=lane>>2, chunk q=lane&3
    {
        int i = lane >> 2, q = lane & 3;
        int node = n0 + i; if (node >= N_NODES) node = 0;
        const uint4* src = (const uint4*)(ncb + (size_t)node * 64 + q * 16);
        uint4 v0 = src[0], v1 = src[1];
        *(uint4*)&nh[i * 104 + q * 16] = v0;
        *(uint4*)&nh[i * 104 + q * 16 + 8] = v1;
        bf16x4 z4 = {0, 0, 0, 0};
        *(bf16x4*)&nh[i * 104 + 80 + q * 4] = z4;
    }

    // gather msg (16 nodes serial; per-node math identical to gather_mean_seq)
    for (int i = 0; i < 16; i++) {
        int node = n0 + i;
        int nodeC = (node < N_NODES) ? node : 0;
        int p0 = off[nodeC], p1 = off[nodeC + 1];
        float sum = 0.f;
        for (int p = p0 + g; p < p1; p += 4)
            sum += bf2f((unsigned int)ecurb[(size_t)p * 16 + r16]);
        sum += __shfl_xor(sum, 16, 64);
        sum += __shfl_xor(sum, 32, 64);
        if (lane < 16) {
            float inv = 1.0f / fmaxf((float)(p1 - p0), 1.0f);
            nh[i * 104 + 64 + r16] = f2bf(sum * inv);
        }
    }
    asm volatile("s_waitcnt lgkmcnt(0)" ::: "memory");
    __builtin_amdgcn_sched_barrier(0);

    // layer1: 4 col-tiles x K=96 (3 MFMA each); relu -> bf16 act2 (stride 72)
#pragma unroll
    for (int t = 0; t < 4; t++) {
        float bv = wsW[O_NODEB0 + t * 16 + r16];   // cols>=56: finite garbage, killed by 0-weights
        f32x4 acc = {bv, bv, bv, bv};
#pragma unroll
        for (int st = 0; st < 3; st++) {
            bf16x8 av = *(const bf16x8*)&nh[r16 * 104 + st * 32 + g * 8];
            bf16x8 bw = *(const bf16x8*)(wn + (t * 16 + r16) * 96 + st * 32 + g * 8);
            acc = __builtin_amdgcn_mfma_f32_16x16x32_bf16(av, bw, acc, 0, 0, 0);
        }
#pragma unroll
        for (int i = 0; i < 4; i++)
            a2w[(g * 4 + i) * 72 + t * 16 + r16] = f2bf(fmaxf(acc[i], 0.f));
    }
    asm volatile("s_waitcnt lgkmcnt(0)" ::: "memory");
    __builtin_amdgcn_sched_barrier(0);

    // layer2: 2 col-tiles x K=64 (2 MFMA each); relu -> ncb n-half
#pragma unroll
    for (int t2 = 0; t2 < 2; t2++) {
        float bv = wsW[O_NODEB1 + t2 * 16 + r16];
        f32x4 acc = {bv, bv, bv, bv};
#pragma unroll
        for (int st = 0; st < 2; st++) {
            bf16x8 av = *(const bf16x8*)&a2w[r16 * 72 + st * 32 + g * 8];
            bf16x8 bw = *(const bf16x8*)(wn + 6144 + (t2 * 16 + r16) * 64 + st * 32 + g * 8);
            acc = __builtin_amdgcn_mfma_f32_16x16x32_bf16(av, bw, acc, 0, 0, 0);
        }
#pragma unroll
        for (int i = 0; i < 4; i++) {
            int node = n0 + g * 4 + i;
            if (node < N_NODES)
                ncb[(size_t)node * 64 + 32 + t2 * 16 + r16] = f2bf(fmaxf(acc[i], 0.f));
        }
    }
}

extern "C" void kernel_launch(void* const* d_in, const int* in_sizes, int n_in,
                              void* d_out, int out_size, void* d_ws, size_t ws_size,
                              hipStream_t stream) {
    (void)in_sizes; (void)n_in; (void)out_size;
    const float* x  = (const float*)d_in[0];
    const int* eidx = (const int*)d_in[1];
    const float* ea = (const float*)d_in[2];
    float* out = (float*)d_out;   // f32 output: 5 slots x E x 16

    // d_ws layout (byte offsets):
    //   wsW @0 (85232) | flags @85232 (16) | cnti @85248 (200000) | off @285248 (200016)
    //   cursor @485264 (200000) | perm @685264 (6400000) | ncb @7085264 (6400000, u16)
    //   wT @13485264 (28672, u16) | msg/wn @13513936 (3200000: f32 msg OR u16 wn tables)
    //   [big] e0b @16714240 | rb0 | rb1 (each 51,200,000 B, bf16 E x 16)
    //   [perm] rcp @170314240 (12,800,000, int2) | pose @183114240 (6,400,000, int)
    char* wsb = (char*)d_ws;
    float* wsW  = (float*)(wsb + 0);
    int* flags  = (int*)(wsb + 85232);
    int* cnti   = (int*)(wsb + 85248);
    int* off    = (int*)(wsb + 285248);
    int* cursor = (int*)(wsb + 485264);
    int* perm   = (int*)(wsb + 685264);
    unsigned short* ncb = (unsigned short*)(wsb + 7085264);
    unsigned short* wT  = (unsigned short*)(wsb + 13485264);
    float* msg  = (float*)(wsb + 13513936);
    unsigned short* wn = (unsigned short*)(wsb + 13513936);   // perm path only (msg unused there)
    const size_t WS_BASE = 16713936ull;
    unsigned short* e0b = (unsigned short*)(wsb + 16714240);
    unsigned short* rb0 = e0b + (size_t)N_EDGES * 16;
    unsigned short* rb1 = rb0 + (size_t)N_EDGES * 16;
    const size_t WS_BIG = 16714240ull + 3ull * 51200000ull;   // ~170.3 MB
    int2* rcp = (int2*)(wsb + 170314240ull);
    int* pose = (int*)(wsb + 183114240ull);
    const size_t WS_PERM = 189514240ull;                      // ~189.5 MB
    if (ws_size < WS_BASE) return;  // refuse to corrupt memory
    const bool big  = (ws_size >= WS_BIG);
    const bool prm  = (ws_size >= WS_PERM);

    WPack P;
    static const int offs[15] = {0, 108, 126, 450, 468, 756, 772, 13572, 13652,
                                 14932, 14948, 19428, 19484, 21276, 21308};
    for (int a = 0; a < 14; a++) P.p[a] = (const float*)d_in[3 + a];
    for (int a = 0; a < 15; a++) P.off[a] = offs[a];

    detect_flags<<<1, 64, 0, stream>>>(eidx, flags);
    copy_w<<<14, 256, 0, stream>>>(P, wsW);
    build_wT<<<56, 256, 0, stream>>>((const float*)d_in[9], (const float*)d_in[11], wT);
    init_nodes<<<196, 256, 0, stream>>>(x, ncb, cnti);
    count_edges<<<N_EDGES / 256, 256, 0, stream>>>(eidx, flags, cnti);
    scan_offsets<<<1, 256, 0, stream>>>(cnti, off, cursor);
    if (prm)
        build_perm<1><<<N_EDGES / 256, 256, 0, stream>>>(eidx, flags, cursor, perm, rcp, pose);
    else
        build_perm<0><<<N_EDGES / 256, 256, 0, stream>>>(eidx, flags, cursor, perm, nullptr, nullptr);

    if (prm) {
        build_wnT<<<32, 256, 0, stream>>>((const float*)d_in[13], (const float*)d_in[15], wn);
        encoder<2><<<N_EDGES / 256, 256, 0, stream>>>(ea, wsW, out, e0b, pose);
        unsigned short* rings[2] = {rb0, rb1};
        for (int t = 1; t <= 6; t++) {
            unsigned short* prevb = (t == 1) ? e0b : rings[(t - 1) & 1];
            unsigned short* curb  = rings[t & 1];
            if (t == 1)
                edge_mfma_perm<0><<<N_EDGES / 128, 256, 0, stream>>>(
                    ncb, e0b, prevb, curb, rcp, perm, wsW, wT, out);
            else
                edge_mfma_perm<1><<<N_EDGES / 128, 256, 0, stream>>>(
                    ncb, e0b, prevb, curb, rcp, perm, wsW, wT,
                    out + (size_t)(t - 2) * N_EDGES * 16);
            if (t < 6)
                node_fused<<<782, 256, 0, stream>>>(off, curb, ncb, wsW, wn);
        }
    } else if (big) {
        encoder<1><<<N_EDGES / 256, 256, 0, stream>>>(ea, wsW, out, e0b, nullptr);
        unsigned short* rings[2] = {rb0, rb1};
        for (int t = 1; t <= 6; t++) {
            unsigned short* prevb = (t == 1) ? e0b : rings[(t - 1) & 1];
            unsigned short* curb  = rings[t & 1];
            if (t == 1)
                edge_mfma_b16<0><<<N_EDGES / 128, 256, 0, stream>>>(
                    ncb, e0b, prevb, curb, eidx, flags, wsW, wT, out);
            else
                edge_mfma_b16<1><<<N_EDGES / 128, 256, 0, stream>>>(
                    ncb, e0b, prevb, curb, eidx, flags, wsW, wT,
                    out + (size_t)(t - 2) * N_EDGES * 16);
            if (t < 6) {
                gather_mean_b16<<<12500, 256, 0, stream>>>(off, perm, curb, msg);
                node_mlp<<<782, 64, 0, stream>>>(msg, ncb, wsW);
            }
        }
    } else {
        encoder<0><<<N_EDGES / 256, 256, 0, stream>>>(ea, wsW, out, nullptr, nullptr);
        const int prevs[6] = {4, 0, 0, 1, 2, 3};
        const int curs[6]  = {0, 0, 1, 2, 3, 4};
        for (int t = 1; t <= 6; t++) {
            edge_mfma<<<N_EDGES / 128, 256, 0, stream>>>(ncb, out, 4, prevs[t - 1],
                                                         curs[t - 1], eidx, flags, wsW,
                                                         wT, out);
            if (t < 6) {
                gather_mean<<<12500, 256, 0, stream>>>(
                    off, perm, out + (size_t)curs[t - 1] * N_EDGES * 16, msg);
                node_mlp<<<782, 64, 0, stream>>>(msg, ncb, wsW);
            }
        }
    }
}